// Round 9
// baseline (354.530 us; speedup 1.0000x reference)
//
#include <hip/hip_runtime.h>

typedef unsigned short u16;
typedef __attribute__((ext_vector_type(2))) float f32x2;
typedef __attribute__((ext_vector_type(4))) float f32x4;
typedef __attribute__((ext_vector_type(8))) short s16x8;
typedef __attribute__((ext_vector_type(8))) u16 u16x8;
typedef __attribute__((ext_vector_type(4))) u16 u16x4;

#define NB 16
#define CD 512
#define NS 4096
#define NHD 8

#define SBAR  __builtin_amdgcn_s_barrier()
#define SCHED __builtin_amdgcn_sched_barrier(0)
#define PRIO1 __builtin_amdgcn_s_setprio(1)
#define PRIO0 __builtin_amdgcn_s_setprio(0)

__device__ __forceinline__ float bf2f(u16 u){
  union { unsigned int i; float f; } z; z.i = ((unsigned int)u) << 16; return z.f;
}
__device__ __forceinline__ u16 f2bf(float f){
  union { float f; unsigned int i; } z; z.f = f;
  unsigned int i = z.i;
  return (u16)((i + 0x7fffu + ((i >> 16) & 1u)) >> 16);
}
__device__ __forceinline__ float gelu_f(float x){
  return 0.5f * x * (1.0f + erff(x * 0.70710678118654752440f));
}
__device__ __forceinline__ void gl_lds16(const u16* g, u16* l){
  __builtin_amdgcn_global_load_lds((const __attribute__((address_space(1))) void*)(g),
                                   (__attribute__((address_space(3))) void*)(l), 16, 0, 0);
}

// ---------------- K0: weights -> bf16 (g1 folded into w_qkv) ----------------
__global__ void prep_w_k(const float* __restrict__ wqkv, const float* __restrict__ g1,
                         const float* __restrict__ wout, u16* __restrict__ w1b,
                         u16* __restrict__ w2b){
  int i = blockIdx.x * 256 + threadIdx.x;
  if (i < 1536*512) {
    w1b[i] = f2bf(wqkv[i] * g1[i & 511]);
  } else {
    int j = i - 1536*512;
    w2b[j] = f2bf(wout[j]);
  }
}

// ------- K1: ChanLN over c, single global read via big-LDS staging ---------
__global__ __launch_bounds__(512) void ln1t_k(const float* __restrict__ fmap,
                                              u16* __restrict__ xlnT){
  int b = blockIdx.y, n0 = blockIdx.x * 32;
  int t = threadIdx.x;
  int lane = t & 63, wv = t >> 6;
  __shared__ float Lb[512][36];
  __shared__ u16 Tt[64][36];
  __shared__ float red1[8][8][4], red2[8][8][4];
  __shared__ float mean_s[32], rstd_s[32];

  int ng = t & 7;
  float s1[4] = {0,0,0,0}, s2[4] = {0,0,0,0};
  const float* fb = fmap + ((size_t)b*CD)*NS + n0 + ng*4;
  #pragma unroll
  for (int it = 0; it < 8; ++it){
    int q = it*512 + t;
    int c = q >> 3;
    f32x4 v = *(const f32x4*)&fb[(size_t)c*NS];
    *(f32x4*)&Lb[c][ng*4] = v;
    #pragma unroll
    for (int j = 0; j < 4; ++j){ s1[j] += v[j]; s2[j] += v[j]*v[j]; }
  }
  #pragma unroll
  for (int off = 8; off < 64; off <<= 1)
    #pragma unroll
    for (int j = 0; j < 4; ++j){
      s1[j] += __shfl_xor(s1[j], off, 64);
      s2[j] += __shfl_xor(s2[j], off, 64);
    }
  if (lane < 8){
    #pragma unroll
    for (int j = 0; j < 4; ++j){ red1[wv][lane][j] = s1[j]; red2[wv][lane][j] = s2[j]; }
  }
  __syncthreads();
  if (t < 32){
    int g = t >> 2, j = t & 3;
    float a = 0.f, bq = 0.f;
    #pragma unroll
    for (int w = 0; w < 8; ++w){ a += red1[w][g][j]; bq += red2[w][g][j]; }
    float mn = a * (1.f/512.f);
    float var = bq * (1.f/512.f) - mn*mn;
    mean_s[t] = mn; rstd_s[t] = rsqrtf(var + 1e-5f);
  }
  __syncthreads();

  for (int ct = 0; ct < 8; ++ct){
    {
      int cl = t >> 3, n4 = (t & 7) * 4;
      f32x4 v = *(const f32x4*)&Lb[ct*64 + cl][n4];
      u16x4 pk;
      #pragma unroll
      for (int j = 0; j < 4; ++j)
        pk[j] = f2bf((v[j] - mean_s[n4+j]) * rstd_s[n4+j]);
      *(u16x4*)&Tt[cl][n4] = pk;
    }
    __syncthreads();
    {
      int nr = t >> 4, c4 = t & 15;
      u16x4 w;
      #pragma unroll
      for (int j = 0; j < 4; ++j) w[j] = Tt[c4*4 + j][nr];
      *(u16x4*)&xlnT[((size_t)b*NS + n0 + nr)*CD + ct*64 + c4*4] = w;
    }
    __syncthreads();
  }
}

// ---------- K2: 128x256 GEMM, BK=32, 4-slot ring, 2 blocks/CU --------------
// 128B-line LDS layout (measured 0-conflict in r8). No manual lgkm wall:
// compiler interleaves ds_read with MFMA (fine-grained lgkmcnt). 3-tile
// stage lead, vmcnt(3) at kt end (2-tile flight maintained, never drain).
__global__ __launch_bounds__(512, 4) void gemm1_k(const u16* __restrict__ A,
                                                  const u16* __restrict__ Bm,
                                                  u16* __restrict__ Cm){
  __shared__ u16 lds[4][12288];   // slot: A[0..4096) 64 lines, B[4096..12288) 128 lines
  int bi = blockIdx.x;
  int xcd = bi & 7, r2 = bi >> 3;
  int oo  = r2 % 12;
  int x   = (r2 / 12) & 15;
  int zl  = r2 / 192;
  int z   = xcd*2 + zl;
  int o0 = oo*128, bn0 = x*256;
  int t = threadIdx.x;
  int lane = t & 63, wv = t >> 6;
  int wm = wv >> 2, wn = wv & 3;
  int fr = lane & 15, fg = lane >> 4;
  const u16* Ab = A + (size_t)o0*512;
  const u16* Bb = Bm + ((size_t)z*NS + bn0)*512;

  int l8  = lane >> 3;
  int c8l = (lane & 7) ^ l8;
  int shf = c8l >> 2;
  int sc  = (c8l & 3) * 8;

  f32x4 acc[4][4];
  #pragma unroll
  for (int i=0;i<4;++i)
    #pragma unroll
    for (int j=0;j<4;++j) acc[i][j] = (f32x4){0.f,0.f,0.f,0.f};
  s16x8 afr[4], bfr[4];

  auto stA = [&](int slot, int kt){
    int L = wv*8 + l8;
    int r = shf*64 + L;
    gl_lds16(Ab + (size_t)r*512 + kt + sc, &lds[slot][wv*512]);
  };
  auto stB = [&](int slot, int kt, int i){
    int L = i*64 + wv*8 + l8;
    int r = shf*128 + L;
    gl_lds16(Bb + (size_t)r*512 + kt + sc, &lds[slot][4096 + i*4096 + wv*512]);
  };
  auto ldA = [&](int slot){
    #pragma unroll
    for (int mi=0;mi<4;++mi){
      int L  = mi*16 + fr;
      int c8 = (wm*4 + fg) ^ (L & 7);
      afr[mi] = *(const s16x8*)&lds[slot][L*64 + c8*8];
    }
  };
  auto ldB = [&](int slot){
    #pragma unroll
    for (int nj=0;nj<4;++nj){
      int L  = (wn&1)*64 + nj*16 + fr;
      int c8 = ((wn>>1)*4 + fg) ^ (L & 7);
      bfr[nj] = *(const s16x8*)&lds[slot][4096 + L*64 + c8*8];
    }
  };

  // prologue: tiles 0,1,2 (3 loads each); wait tile 0 (6 outstanding)
  stA(0,0);  stB(0,0,0);  stB(0,0,1);
  stA(1,32); stB(1,32,0); stB(1,32,1);
  stA(2,64); stB(2,64,0); stB(2,64,1);
  asm volatile("s_waitcnt vmcnt(6)" ::: "memory");
  SBAR; SCHED;

  #pragma unroll
  for (int kt=0; kt<16; ++kt){
    int slot = kt & 3;
    ldA(slot); ldB(slot);
    if (kt < 13){
      int ns = (kt+3) & 3, kn = (kt+3)*32;
      stA(ns,kn); stB(ns,kn,0); stB(ns,kn,1);
    }
    PRIO1;
    #pragma unroll
    for (int mi=0;mi<4;++mi)
      #pragma unroll
      for (int nj=0;nj<4;++nj)
        acc[mi][nj] = __builtin_amdgcn_mfma_f32_16x16x32_bf16(
            afr[mi], bfr[nj], acc[mi][nj], 0,0,0);
    PRIO0;
    if (kt < 13)       asm volatile("s_waitcnt vmcnt(3)" ::: "memory");
    else if (kt == 13) asm volatile("s_waitcnt vmcnt(0)" ::: "memory");
    SBAR; SCHED;
  }

  size_t cb = (size_t)z * 1536 * NS;
  #pragma unroll
  for (int mi=0;mi<4;++mi)
    #pragma unroll
    for (int nj=0;nj<4;++nj){
      int row = o0 + wm*64 + mi*16 + fg*4;
      int col = bn0 + wn*64 + nj*16 + fr;
      #pragma unroll
      for (int r=0;r<4;++r)
        Cm[cb + (size_t)(row+r)*NS + col] = f2bf(acc[mi][nj][r]);
    }
}

// ------ K6: full-column GEMM (512x128) + fused final ChanLN -> d_out -------
// 128B-line layout (0-conflict family), one barrier per kt, no lgkm walls.
__global__ __launch_bounds__(512, 2) void gemm2ln_k(const u16* __restrict__ A,
                                                    const u16* __restrict__ Bm,
                                                    const float* __restrict__ g2,
                                                    float* __restrict__ out){
  __shared__ u16 lds[3][20480];   // slot: A 256 lines (32KB), B 64 lines (8KB)
  int x = blockIdx.x, z = blockIdx.y;
  int n0 = x*128;
  int t = threadIdx.x;
  int lane = t & 63, wv = t >> 6;
  int wm = wv >> 1, wn = wv & 1;
  int fr = lane & 15, fg = lane >> 4;
  const u16* Ab = A;
  const u16* Bb = Bm + ((size_t)z*NS + n0)*512;

  int l8  = lane >> 3;
  int c8d = lane & 7;

  f32x4 acc[8][4];
  #pragma unroll
  for (int i=0;i<8;++i)
    #pragma unroll
    for (int j=0;j<4;++j) acc[i][j] = (f32x4){0.f,0.f,0.f,0.f};
  s16x8 afr[4], bfr[4];

  auto stA = [&](int slot, int kt, int bt){
    int L  = bt*64 + wv*8 + l8;
    int q  = c8d ^ (l8 & 7);         // half*4 + cgrp
    int r  = (q >> 2)*256 + L;
    int col = kt + (q & 3)*8;
    gl_lds16(Ab + (size_t)r*512 + col, &lds[slot][(bt*64 + wv*8)*64]);
  };
  auto stB = [&](int slot, int kt){
    int L  = wv*8 + l8;
    int q  = c8d ^ (l8 & 7);
    int r  = (q >> 2)*64 + L;
    int col = kt + (q & 3)*8;
    gl_lds16(Bb + (size_t)r*512 + col, &lds[slot][16384 + (wv*8)*64]);
  };
  auto ldA = [&](int slot, int h){
    #pragma unroll
    for (int mi=0;mi<4;++mi){
      int R = wm*128 + (h*4+mi)*16 + fr;
      int L = R & 255, half = R >> 8;
      int c8 = (half*4 + fg) ^ (L & 7);
      afr[mi] = *(const s16x8*)&lds[slot][L*64 + c8*8];
    }
  };
  auto ldB = [&](int slot){
    #pragma unroll
    for (int nj=0;nj<4;++nj){
      int R = wn*64 + nj*16 + fr;
      int L = R & 63, half = R >> 6;
      int c8 = (half*4 + fg) ^ (L & 7);
      bfr[nj] = *(const s16x8*)&lds[slot][16384 + L*64 + c8*8];
    }
  };
  auto mm16 = [&](int h){
    #pragma unroll
    for (int mi=0;mi<4;++mi)
      #pragma unroll
      for (int nj=0;nj<4;++nj)
        acc[h*4+mi][nj] = __builtin_amdgcn_mfma_f32_16x16x32_bf16(
            afr[mi], bfr[nj], acc[h*4+mi][nj], 0,0,0);
  };

  // prologue: tiles 0,1 (5 loads each)
  #pragma unroll
  for (int p=0;p<2;++p){ stA(p,p*32,0); stA(p,p*32,1); stB(p,p*32); stA(p,p*32,2); stA(p,p*32,3); }
  asm volatile("s_waitcnt vmcnt(5)" ::: "memory");
  SBAR; SCHED;

  #pragma unroll
  for (int kt=0; kt<16; ++kt){
    int slot = kt%3;
    ldA(slot,0); ldB(slot);
    if (kt<14){
      int ns = (kt+2)%3, kn = (kt+2)*32;
      stA(ns,kn,0); stA(ns,kn,1); stB(ns,kn); stA(ns,kn,2); stA(ns,kn,3);
    }
    PRIO1; mm16(0); PRIO0;
    ldA(slot,1);
    PRIO1; mm16(1); PRIO0;
    if (kt<14)       asm volatile("s_waitcnt vmcnt(5)" ::: "memory");
    else if (kt==14) asm volatile("s_waitcnt vmcnt(0)" ::: "memory");
    SBAR; SCHED;
  }

  // ---- fused LN2: stats over all 512 rows per n-col, then write d_out ----
  __syncthreads();
  float* red1 = (float*)&lds[0][0];
  float* red2 = red1 + 512;
  float* ms   = red2 + 512;
  float* rs   = ms + 128;
  float s1[4], s2[4];
  #pragma unroll
  for (int nj=0;nj<4;++nj){
    float a = 0.f, b2 = 0.f;
    #pragma unroll
    for (int mi=0;mi<8;++mi)
      #pragma unroll
      for (int r=0;r<4;++r){ float v = acc[mi][nj][r]; a += v; b2 += v*v; }
    s1[nj] = a; s2[nj] = b2;
  }
  #pragma unroll
  for (int off=16; off<64; off<<=1)
    #pragma unroll
    for (int nj=0;nj<4;++nj){
      s1[nj] += __shfl_xor(s1[nj], off, 64);
      s2[nj] += __shfl_xor(s2[nj], off, 64);
    }
  if (fg == 0){
    #pragma unroll
    for (int nj=0;nj<4;++nj){
      int c = wn*64 + nj*16 + fr;
      red1[wm*128 + c] = s1[nj];
      red2[wm*128 + c] = s2[nj];
    }
  }
  __syncthreads();
  if (t < 128){
    float a  = red1[t] + red1[128+t] + red1[256+t] + red1[384+t];
    float b2 = red2[t] + red2[128+t] + red2[256+t] + red2[384+t];
    float mn = a * (1.f/512.f);
    float var = b2 * (1.f/512.f) - mn*mn;
    ms[t] = mn; rs[t] = rsqrtf(var + 1e-5f);
  }
  __syncthreads();
  float mc[4], rc[4];
  #pragma unroll
  for (int nj=0;nj<4;++nj){
    int c = wn*64 + nj*16 + fr;
    mc[nj] = ms[c]; rc[nj] = rs[c];
  }
  float* ob = out + (size_t)z*CD*NS + n0;
  #pragma unroll
  for (int mi=0;mi<8;++mi)
    #pragma unroll
    for (int r=0;r<4;++r){
      int row = wm*128 + mi*16 + fg*4 + r;
      float gg = g2[row];
      #pragma unroll
      for (int nj=0;nj<4;++nj)
        ob[(size_t)row*NS + wn*64 + nj*16 + fr] = (acc[mi][nj][r] - mc[nj])*rc[nj]*gg;
    }
}

// ------- K4: context partials (online k-softmax, local max per chunk) ------
__global__ __launch_bounds__(256) void ctxpart_k(const u16* __restrict__ qkv,
                                                 float* __restrict__ part,
                                                 float* __restrict__ mS){
  int chunk = blockIdx.x, bh = blockIdx.y;
  int b = bh >> 3, h = bh & 7;
  int t = threadIdx.x;
  int lane = t & 63, wv = t >> 6;
  int fr = lane & 15, fg = lane >> 4;
  __shared__ u16 KT[64*128];
  __shared__ u16 VT[64*128];
  __shared__ float invn_s[128];
  const u16* kb = qkv + ((size_t)(b*1536 + 512  + h*64))*NS;
  const u16* vb = qkv + ((size_t)(b*1536 + 1024 + h*64))*NS;
  int d = t >> 2, q = t & 3;

  float mloc = -3.0e38f;
  #pragma unroll
  for (int nt = 0; nt < 4; ++nt)
    #pragma unroll
    for (int s = 0; s < 4; ++s){
      u16x8 kk = *(const u16x8*)&kb[(size_t)d*NS + chunk*512 + nt*128 + q*32 + s*8];
      #pragma unroll
      for (int j = 0; j < 8; ++j) mloc = fmaxf(mloc, bf2f(kk[j]));
    }
  mloc = fmaxf(mloc, __shfl_xor(mloc, 1, 64));
  mloc = fmaxf(mloc, __shfl_xor(mloc, 2, 64));
  float sloc = 0.f;

  f32x4 acc[4][4];
  #pragma unroll
  for (int i=0;i<4;++i)
    #pragma unroll
    for (int j=0;j<4;++j) acc[i][j] = (f32x4){0.f,0.f,0.f,0.f};

  for (int nt = 0; nt < 4; ++nt){
    int n0 = chunk*512 + nt*128;
    if (nt) __syncthreads();
    u16x8 kreg[4];
    #pragma unroll
    for (int s = 0; s < 4; ++s){
      int c0 = q*32 + s*8;
      u16x8 vv = *(const u16x8*)&vb[(size_t)d*NS + n0 + c0];
      *(u16x8*)&VT[d*128 + (c0 ^ ((d&7)<<3))] = vv;
      kreg[s] = *(const u16x8*)&kb[(size_t)d*NS + n0 + c0];
    }
    __syncthreads();
    if (t < 128){
      float ss = 0.f;
      #pragma unroll
      for (int e = 0; e < 64; ++e){
        float xv = bf2f(VT[e*128 + (t ^ ((e&7)<<3))]);
        ss += xv*xv;
      }
      invn_s[t] = rsqrtf(ss);
    }
    __syncthreads();
    #pragma unroll
    for (int s = 0; s < 4; ++s){
      int c0 = q*32 + s*8;
      u16x8 kk = kreg[s];
      u16x8 ek;
      #pragma unroll
      for (int j = 0; j < 8; ++j){
        float e = __expf(bf2f(kk[j]) - mloc);
        sloc += e;
        ek[j] = f2bf(e * invn_s[c0 + j]);
      }
      *(u16x8*)&KT[d*128 + (c0 ^ ((d&7)<<3))] = ek;
    }
    __syncthreads();
    int kc = wv*32 + fg*8;
    s16x8 af[4], bfr[4];
    #pragma unroll
    for (int i=0;i<4;++i){
      int ra = i*16 + fr;
      af[i]  = *(const s16x8*)&KT[ra*128 + (kc ^ ((ra&7)<<3))];
      bfr[i] = *(const s16x8*)&VT[ra*128 + (kc ^ ((ra&7)<<3))];
    }
    #pragma unroll
    for (int i=0;i<4;++i)
      #pragma unroll
      for (int j=0;j<4;++j)
        acc[i][j] = __builtin_amdgcn_mfma_f32_16x16x32_bf16(af[i], bfr[j], acc[i][j], 0,0,0);
  }

  sloc += __shfl_xor(sloc, 1, 64);
  sloc += __shfl_xor(sloc, 2, 64);
  if (q == 0){
    size_t mb = ((size_t)bh*8 + chunk)*128;
    mS[mb + d]      = mloc;
    mS[mb + 64 + d] = sloc;
  }

  float* buf0 = (float*)KT;
  float* buf1 = (float*)VT;
  auto dump = [&](float* bf){
    #pragma unroll
    for (int i=0;i<4;++i)
      #pragma unroll
      for (int j=0;j<4;++j)
        #pragma unroll
        for (int r=0;r<4;++r) bf[((i*4+j)*4+r)*64 + lane] = acc[i][j][r];
  };
  auto addin = [&](float* bf){
    #pragma unroll
    for (int i=0;i<4;++i)
      #pragma unroll
      for (int j=0;j<4;++j)
        #pragma unroll
        for (int r=0;r<4;++r) acc[i][j][r] += bf[((i*4+j)*4+r)*64 + lane];
  };
  __syncthreads();
  if (wv==1) dump(buf0);
  if (wv==3) dump(buf1);
  __syncthreads();
  if (wv==0) addin(buf0);
  if (wv==2) addin(buf1);
  __syncthreads();
  if (wv==2) dump(buf0);
  __syncthreads();
  if (wv==0){
    addin(buf0);
    float* pp = part + ((size_t)bh*8 + chunk)*4096;
    #pragma unroll
    for (int i=0;i<4;++i)
      #pragma unroll
      for (int j=0;j<4;++j)
        #pragma unroll
        for (int r=0;r<4;++r)
          pp[(i*16+fg*4+r)*64 + j*16+fr] = acc[i][j][r];
  }
}

// ---- K4b: merge 8 chunk partials with online-softmax scales -> ctx --------
__global__ void ctxred_k(const float* __restrict__ part, const float* __restrict__ mS,
                         float* __restrict__ ctx){
  int bh = blockIdx.x, t = threadIdx.x;
  __shared__ float fs[8][64];
  if (t < 64){
    int d = t;
    float mc[8];
    float mx = -3.0e38f;
    #pragma unroll
    for (int c=0;c<8;++c){ mc[c] = mS[((size_t)bh*8 + c)*128 + d]; mx = fmaxf(mx, mc[c]); }
    float es[8]; float denom = 0.f;
    #pragma unroll
    for (int c=0;c<8;++c){
      es[c] = __expf(mc[c] - mx);
      denom += es[c] * mS[((size_t)bh*8 + c)*128 + 64 + d];
    }
    float inv = 1.0f / (denom * 4096.0f);
    #pragma unroll
    for (int c=0;c<8;++c) fs[c][d] = es[c] * inv;
  }
  __syncthreads();
  #pragma unroll
  for (int i=0;i<16;++i){
    int idx = t + i*256;
    int d = idx >> 6;
    float s = 0.f;
    #pragma unroll
    for (int ch=0; ch<8; ++ch) s += fs[ch][d] * part[((size_t)bh*8 + ch)*4096 + idx];
    ctx[(size_t)bh*4096 + idx] = s;
  }
}

// ------- K5: out = softmax_feat(q)*scale @ ctx  via MFMA, GELU, gT[b][n][c] -
__global__ __launch_bounds__(256) void attnout_k(const u16* __restrict__ qkv,
                                                 const float* __restrict__ ctx,
                                                 u16* __restrict__ gT){
  int bh = blockIdx.y;
  int b = bh >> 3, h = bh & 7;
  int n0 = blockIdx.x * 256;
  int t = threadIdx.x;
  int lane = t & 63, wv = t >> 6;
  int fr = lane & 15, fg = lane >> 4;
  __shared__ u16 P[256][72];
  __shared__ u16 cT[64][72];

  const float* cs = ctx + (size_t)bh*4096;
  #pragma unroll
  for (int i=0;i<16;++i){
    int idx = i*256 + t;
    int d = idx >> 6, e = idx & 63;
    cT[e][d] = f2bf(cs[idx]);
  }

  const u16* qb = qkv + ((size_t)(b*1536 + h*64))*NS + n0 + t;
  float p[64];
  #pragma unroll
  for (int d=0; d<64; ++d) p[d] = bf2f(qb[(size_t)d*NS]);
  float m = p[0];
  #pragma unroll
  for (int d=1; d<64; ++d) m = fmaxf(m, p[d]);
  float s = 0.f;
  #pragma unroll
  for (int d=0; d<64; ++d){ p[d] = __expf(p[d]-m); s += p[d]; }
  float inv = 0.125f / s;
  #pragma unroll
  for (int d0=0; d0<8; ++d0){
    u16x8 pk;
    #pragma unroll
    for (int j=0;j<8;++j) pk[j] = f2bf(p[d0*8+j] * inv);
    *(u16x8*)&P[t][d0*8] = pk;
  }
  __syncthreads();

  f32x4 acc[4][4];
  #pragma unroll
  for (int i=0;i<4;++i)
    #pragma unroll
    for (int j=0;j<4;++j) acc[i][j] = (f32x4){0.f,0.f,0.f,0.f};
  #pragma unroll
  for (int k=0; k<2; ++k){
    s16x8 af[4], bfr[4];
    #pragma unroll
    for (int i=0;i<4;++i){
      af[i]  = *(const s16x8*)&P[wv*64 + i*16 + fr][k*32 + fg*8];
      bfr[i] = *(const s16x8*)&cT[i*16 + fr][k*32 + fg*8];
    }
    #pragma unroll
    for (int i=0;i<4;++i)
      #pragma unroll
      for (int j=0;j<4;++j)
        acc[i][j] = __builtin_amdgcn_mfma_f32_16x16x32_bf16(af[i], bfr[j], acc[i][j], 0,0,0);
  }

  #pragma unroll
  for (int i=0;i<4;++i)
    #pragma unroll
    for (int j=0;j<4;++j)
      #pragma unroll
      for (int r=0;r<4;++r)
        P[wv*64 + i*16 + fg*4 + r][j*16 + fr] = f2bf(gelu_f(acc[i][j][r]));

  int sub = lane >> 4, e4 = (lane & 15) * 4;
  #pragma unroll
  for (int it=0; it<16; ++it){
    int row = wv*64 + it*4 + sub;
    *(u16x4*)&gT[((size_t)b*NS + n0 + row)*CD + h*64 + e4] = *(u16x4*)&P[row][e4];
  }
}

extern "C" void kernel_launch(void* const* d_in, const int* in_sizes, int n_in,
                              void* d_out, int out_size, void* d_ws, size_t ws_size,
                              hipStream_t stream) {
  const float* fmap = (const float*)d_in[0];
  const float* g1   = (const float*)d_in[1];
  const float* wqkv = (const float*)d_in[2];
  const float* wout = (const float*)d_in[3];
  const float* g2   = (const float*)d_in[4];
  float* out = (float*)d_out;

  char* ws = (char*)d_ws;
  size_t off = 0;
  auto alloc = [&](size_t bytes) -> void* {
    void* p = ws + off;
    off += (bytes + 255) & ~(size_t)255;
    return p;
  };
  u16*   qkv  = (u16*)alloc((size_t)16*1536*4096*2);
  u16*   xlnT = (u16*)alloc((size_t)16*4096*512*2);    // reused as gT
  u16*   gT   = xlnT;
  float* part = (float*)alloc((size_t)128*8*4096*4);
  float* mS   = (float*)alloc((size_t)128*8*128*4);
  float* ctx  = (float*)alloc((size_t)128*4096*4);
  u16*   w1b  = (u16*)alloc((size_t)1536*512*2);
  u16*   w2b  = (u16*)alloc((size_t)512*512*2);
  if (off > ws_size) return;

  prep_w_k<<<4096, 256, 0, stream>>>(wqkv, g1, wout, w1b, w2b);
  ln1t_k<<<dim3(128,16), 512, 0, stream>>>(fmap, xlnT);
  gemm1_k<<<3072, 512, 0, stream>>>(w1b, xlnT, qkv);
  ctxpart_k<<<dim3(8,128), 256, 0, stream>>>(qkv, part, mS);
  ctxred_k<<<128, 256, 0, stream>>>(part, mS, ctx);
  attnout_k<<<dim3(16,128), 256, 0, stream>>>(qkv, ctx, gT);
  gemm2ln_k<<<dim3(32,16), 512, 0, stream>>>(w2b, gT, g2, out);
}

// Round 10
// 340.513 us; speedup vs baseline: 1.0412x; 1.0412x over previous
//
#include <hip/hip_runtime.h>

typedef unsigned short u16;
typedef __attribute__((ext_vector_type(2))) float f32x2;
typedef __attribute__((ext_vector_type(4))) float f32x4;
typedef __attribute__((ext_vector_type(8))) short s16x8;
typedef __attribute__((ext_vector_type(8))) u16 u16x8;
typedef __attribute__((ext_vector_type(4))) u16 u16x4;

#define NB 16
#define CD 512
#define NS 4096
#define NHD 8

#define SBAR  __builtin_amdgcn_s_barrier()
#define SCHED __builtin_amdgcn_sched_barrier(0)
#define PRIO1 __builtin_amdgcn_s_setprio(1)
#define PRIO0 __builtin_amdgcn_s_setprio(0)

__device__ __forceinline__ float bf2f(u16 u){
  union { unsigned int i; float f; } z; z.i = ((unsigned int)u) << 16; return z.f;
}
__device__ __forceinline__ u16 f2bf(float f){
  union { float f; unsigned int i; } z; z.f = f;
  unsigned int i = z.i;
  return (u16)((i + 0x7fffu + ((i >> 16) & 1u)) >> 16);
}
__device__ __forceinline__ float gelu_f(float x){
  return 0.5f * x * (1.0f + erff(x * 0.70710678118654752440f));
}
__device__ __forceinline__ void gl_lds16(const u16* g, u16* l){
  __builtin_amdgcn_global_load_lds((const __attribute__((address_space(1))) void*)(g),
                                   (__attribute__((address_space(3))) void*)(l), 16, 0, 0);
}

// ---------------- K0: weights -> bf16 (g1 folded into w_qkv) ----------------
__global__ void prep_w_k(const float* __restrict__ wqkv, const float* __restrict__ g1,
                         const float* __restrict__ wout, u16* __restrict__ w1b,
                         u16* __restrict__ w2b){
  int i = blockIdx.x * 256 + threadIdx.x;
  if (i < 1536*512) {
    w1b[i] = f2bf(wqkv[i] * g1[i & 511]);
  } else {
    int j = i - 1536*512;
    w2b[j] = f2bf(wout[j]);
  }
}

// ------- K1: ChanLN over c, single global read via big-LDS staging ---------
__global__ __launch_bounds__(512) void ln1t_k(const float* __restrict__ fmap,
                                              u16* __restrict__ xlnT){
  int b = blockIdx.y, n0 = blockIdx.x * 32;
  int t = threadIdx.x;
  int lane = t & 63, wv = t >> 6;
  __shared__ float Lb[512][36];
  __shared__ u16 Tt[64][36];
  __shared__ float red1[8][8][4], red2[8][8][4];
  __shared__ float mean_s[32], rstd_s[32];

  int ng = t & 7;
  float s1[4] = {0,0,0,0}, s2[4] = {0,0,0,0};
  const float* fb = fmap + ((size_t)b*CD)*NS + n0 + ng*4;
  #pragma unroll
  for (int it = 0; it < 8; ++it){
    int q = it*512 + t;
    int c = q >> 3;
    f32x4 v = *(const f32x4*)&fb[(size_t)c*NS];
    *(f32x4*)&Lb[c][ng*4] = v;
    #pragma unroll
    for (int j = 0; j < 4; ++j){ s1[j] += v[j]; s2[j] += v[j]*v[j]; }
  }
  #pragma unroll
  for (int off = 8; off < 64; off <<= 1)
    #pragma unroll
    for (int j = 0; j < 4; ++j){
      s1[j] += __shfl_xor(s1[j], off, 64);
      s2[j] += __shfl_xor(s2[j], off, 64);
    }
  if (lane < 8){
    #pragma unroll
    for (int j = 0; j < 4; ++j){ red1[wv][lane][j] = s1[j]; red2[wv][lane][j] = s2[j]; }
  }
  __syncthreads();
  if (t < 32){
    int g = t >> 2, j = t & 3;
    float a = 0.f, bq = 0.f;
    #pragma unroll
    for (int w = 0; w < 8; ++w){ a += red1[w][g][j]; bq += red2[w][g][j]; }
    float mn = a * (1.f/512.f);
    float var = bq * (1.f/512.f) - mn*mn;
    mean_s[t] = mn; rstd_s[t] = rsqrtf(var + 1e-5f);
  }
  __syncthreads();

  for (int ct = 0; ct < 8; ++ct){
    {
      int cl = t >> 3, n4 = (t & 7) * 4;
      f32x4 v = *(const f32x4*)&Lb[ct*64 + cl][n4];
      u16x4 pk;
      #pragma unroll
      for (int j = 0; j < 4; ++j)
        pk[j] = f2bf((v[j] - mean_s[n4+j]) * rstd_s[n4+j]);
      *(u16x4*)&Tt[cl][n4] = pk;
    }
    __syncthreads();
    {
      int nr = t >> 4, c4 = t & 15;
      u16x4 w;
      #pragma unroll
      for (int j = 0; j < 4; ++j) w[j] = Tt[c4*4 + j][nr];
      *(u16x4*)&xlnT[((size_t)b*NS + n0 + nr)*CD + ct*64 + c4*4] = w;
    }
    __syncthreads();
  }
}

// ---------- K2: 128x256 GEMM, BK=32, 3-slot ring, 2 blocks/CU --------------
// r8 geometry exactly (LDS 72KB, 0-conflict 128B-line layout, vmcnt(3)),
// ONLY delta vs r8: no lgkmcnt(0)/sched_barrier wall between ds_read and
// MFMA -- compiler emits fine-grained lgkmcnt interleave (m97).
__global__ __launch_bounds__(512, 4) void gemm1_k(const u16* __restrict__ A,
                                                  const u16* __restrict__ Bm,
                                                  u16* __restrict__ Cm){
  __shared__ u16 lds[3][12288];   // slot: A[0..4096) 64 lines, B[4096..12288) 128 lines
  int bi = blockIdx.x;
  int xcd = bi & 7, r2 = bi >> 3;
  int oo  = r2 % 12;
  int x   = (r2 / 12) & 15;
  int zl  = r2 / 192;
  int z   = xcd*2 + zl;
  int o0 = oo*128, bn0 = x*256;
  int t = threadIdx.x;
  int lane = t & 63, wv = t >> 6;
  int wm = wv >> 2, wn = wv & 3;
  int fr = lane & 15, fg = lane >> 4;
  const u16* Ab = A + (size_t)o0*512;
  const u16* Bb = Bm + ((size_t)z*NS + bn0)*512;

  int l8  = lane >> 3;
  int c8l = (lane & 7) ^ l8;
  int shf = c8l >> 2;
  int sc  = (c8l & 3) * 8;

  f32x4 acc[4][4];
  #pragma unroll
  for (int i=0;i<4;++i)
    #pragma unroll
    for (int j=0;j<4;++j) acc[i][j] = (f32x4){0.f,0.f,0.f,0.f};
  s16x8 afr[4], bfr[4];

  auto stA = [&](int slot, int kt){
    int L = wv*8 + l8;
    int r = shf*64 + L;
    gl_lds16(Ab + (size_t)r*512 + kt + sc, &lds[slot][wv*512]);
  };
  auto stB = [&](int slot, int kt, int i){
    int L = i*64 + wv*8 + l8;
    int r = shf*128 + L;
    gl_lds16(Bb + (size_t)r*512 + kt + sc, &lds[slot][4096 + i*4096 + wv*512]);
  };
  auto ldA = [&](int slot){
    #pragma unroll
    for (int mi=0;mi<4;++mi){
      int L  = mi*16 + fr;
      int c8 = (wm*4 + fg) ^ (L & 7);
      afr[mi] = *(const s16x8*)&lds[slot][L*64 + c8*8];
    }
  };
  auto ldB = [&](int slot){
    #pragma unroll
    for (int nj=0;nj<4;++nj){
      int L  = (wn&1)*64 + nj*16 + fr;
      int c8 = ((wn>>1)*4 + fg) ^ (L & 7);
      bfr[nj] = *(const s16x8*)&lds[slot][4096 + L*64 + c8*8];
    }
  };

  // prologue: tiles 0,1 staged; wait tile 0 (3 outstanding)
  stA(0,0);  stB(0,0,0);  stB(0,0,1);
  stA(1,32); stB(1,32,0); stB(1,32,1);
  asm volatile("s_waitcnt vmcnt(3)" ::: "memory");
  SBAR; SCHED;

  #pragma unroll
  for (int kt=0; kt<16; ++kt){
    int slot = kt % 3;
    ldA(slot); ldB(slot);
    if (kt < 14){
      int ns = (kt+2)%3, kn = (kt+2)*32;
      stA(ns,kn); stB(ns,kn,0); stB(ns,kn,1);
    }
    PRIO1;
    #pragma unroll
    for (int mi=0;mi<4;++mi)
      #pragma unroll
      for (int nj=0;nj<4;++nj)
        acc[mi][nj] = __builtin_amdgcn_mfma_f32_16x16x32_bf16(
            afr[mi], bfr[nj], acc[mi][nj], 0,0,0);
    PRIO0;
    if (kt < 14)       asm volatile("s_waitcnt vmcnt(3)" ::: "memory");
    else if (kt == 14) asm volatile("s_waitcnt vmcnt(0)" ::: "memory");
    SBAR; SCHED;
  }

  size_t cb = (size_t)z * 1536 * NS;
  #pragma unroll
  for (int mi=0;mi<4;++mi)
    #pragma unroll
    for (int nj=0;nj<4;++nj){
      int row = o0 + wm*64 + mi*16 + fg*4;
      int col = bn0 + wn*64 + nj*16 + fr;
      #pragma unroll
      for (int r=0;r<4;++r)
        Cm[cb + (size_t)(row+r)*NS + col] = f2bf(acc[mi][nj][r]);
    }
}

// ------ K6: full-column GEMM (512x128) + fused final ChanLN -> d_out -------
__global__ __launch_bounds__(512, 2) void gemm2ln_k(const u16* __restrict__ A,
                                                    const u16* __restrict__ Bm,
                                                    const float* __restrict__ g2,
                                                    float* __restrict__ out){
  __shared__ u16 lds[3][20480];   // slot: A 256 lines (32KB), B 64 lines (8KB)
  int x = blockIdx.x, z = blockIdx.y;
  int n0 = x*128;
  int t = threadIdx.x;
  int lane = t & 63, wv = t >> 6;
  int wm = wv >> 1, wn = wv & 1;
  int fr = lane & 15, fg = lane >> 4;
  const u16* Ab = A;
  const u16* Bb = Bm + ((size_t)z*NS + n0)*512;

  int l8  = lane >> 3;
  int c8d = lane & 7;

  f32x4 acc[8][4];
  #pragma unroll
  for (int i=0;i<8;++i)
    #pragma unroll
    for (int j=0;j<4;++j) acc[i][j] = (f32x4){0.f,0.f,0.f,0.f};
  s16x8 afr[4], bfr[4];

  auto stA = [&](int slot, int kt, int bt){
    int L  = bt*64 + wv*8 + l8;
    int q  = c8d ^ (l8 & 7);
    int r  = (q >> 2)*256 + L;
    int col = kt + (q & 3)*8;
    gl_lds16(Ab + (size_t)r*512 + col, &lds[slot][(bt*64 + wv*8)*64]);
  };
  auto stB = [&](int slot, int kt){
    int L  = wv*8 + l8;
    int q  = c8d ^ (l8 & 7);
    int r  = (q >> 2)*64 + L;
    int col = kt + (q & 3)*8;
    gl_lds16(Bb + (size_t)r*512 + col, &lds[slot][16384 + (wv*8)*64]);
  };
  auto ldA = [&](int slot, int h){
    #pragma unroll
    for (int mi=0;mi<4;++mi){
      int R = wm*128 + (h*4+mi)*16 + fr;
      int L = R & 255, half = R >> 8;
      int c8 = (half*4 + fg) ^ (L & 7);
      afr[mi] = *(const s16x8*)&lds[slot][L*64 + c8*8];
    }
  };
  auto ldB = [&](int slot){
    #pragma unroll
    for (int nj=0;nj<4;++nj){
      int R = wn*64 + nj*16 + fr;
      int L = R & 63, half = R >> 6;
      int c8 = (half*4 + fg) ^ (L & 7);
      bfr[nj] = *(const s16x8*)&lds[slot][16384 + L*64 + c8*8];
    }
  };
  auto mm16 = [&](int h){
    #pragma unroll
    for (int mi=0;mi<4;++mi)
      #pragma unroll
      for (int nj=0;nj<4;++nj)
        acc[h*4+mi][nj] = __builtin_amdgcn_mfma_f32_16x16x32_bf16(
            afr[mi], bfr[nj], acc[h*4+mi][nj], 0,0,0);
  };

  #pragma unroll
  for (int p=0;p<2;++p){ stA(p,p*32,0); stA(p,p*32,1); stB(p,p*32); stA(p,p*32,2); stA(p,p*32,3); }
  asm volatile("s_waitcnt vmcnt(5)" ::: "memory");
  SBAR; SCHED;

  #pragma unroll
  for (int kt=0; kt<16; ++kt){
    int slot = kt%3;
    ldA(slot,0); ldB(slot);
    if (kt<14){
      int ns = (kt+2)%3, kn = (kt+2)*32;
      stA(ns,kn,0); stA(ns,kn,1); stB(ns,kn); stA(ns,kn,2); stA(ns,kn,3);
    }
    PRIO1; mm16(0); PRIO0;
    ldA(slot,1);
    PRIO1; mm16(1); PRIO0;
    if (kt<14)       asm volatile("s_waitcnt vmcnt(5)" ::: "memory");
    else if (kt==14) asm volatile("s_waitcnt vmcnt(0)" ::: "memory");
    SBAR; SCHED;
  }

  // ---- fused LN2: stats over all 512 rows per n-col, then write d_out ----
  __syncthreads();
  float* red1 = (float*)&lds[0][0];
  float* red2 = red1 + 512;
  float* ms   = red2 + 512;
  float* rs   = ms + 128;
  float s1[4], s2[4];
  #pragma unroll
  for (int nj=0;nj<4;++nj){
    float a = 0.f, b2 = 0.f;
    #pragma unroll
    for (int mi=0;mi<8;++mi)
      #pragma unroll
      for (int r=0;r<4;++r){ float v = acc[mi][nj][r]; a += v; b2 += v*v; }
    s1[nj] = a; s2[nj] = b2;
  }
  #pragma unroll
  for (int off=16; off<64; off<<=1)
    #pragma unroll
    for (int nj=0;nj<4;++nj){
      s1[nj] += __shfl_xor(s1[nj], off, 64);
      s2[nj] += __shfl_xor(s2[nj], off, 64);
    }
  if (fg == 0){
    #pragma unroll
    for (int nj=0;nj<4;++nj){
      int c = wn*64 + nj*16 + fr;
      red1[wm*128 + c] = s1[nj];
      red2[wm*128 + c] = s2[nj];
    }
  }
  __syncthreads();
  if (t < 128){
    float a  = red1[t] + red1[128+t] + red1[256+t] + red1[384+t];
    float b2 = red2[t] + red2[128+t] + red2[256+t] + red2[384+t];
    float mn = a * (1.f/512.f);
    float var = b2 * (1.f/512.f) - mn*mn;
    ms[t] = mn; rs[t] = rsqrtf(var + 1e-5f);
  }
  __syncthreads();
  float mc[4], rc[4];
  #pragma unroll
  for (int nj=0;nj<4;++nj){
    int c = wn*64 + nj*16 + fr;
    mc[nj] = ms[c]; rc[nj] = rs[c];
  }
  float* ob = out + (size_t)z*CD*NS + n0;
  #pragma unroll
  for (int mi=0;mi<8;++mi)
    #pragma unroll
    for (int r=0;r<4;++r){
      int row = wm*128 + mi*16 + fg*4 + r;
      float gg = g2[row];
      #pragma unroll
      for (int nj=0;nj<4;++nj)
        ob[(size_t)row*NS + wn*64 + nj*16 + fr] = (acc[mi][nj][r] - mc[nj])*rc[nj]*gg;
    }
}

// ------- K4: context partials (online k-softmax, local max per chunk) ------
__global__ __launch_bounds__(256) void ctxpart_k(const u16* __restrict__ qkv,
                                                 float* __restrict__ part,
                                                 float* __restrict__ mS){
  int chunk = blockIdx.x, bh = blockIdx.y;
  int b = bh >> 3, h = bh & 7;
  int t = threadIdx.x;
  int lane = t & 63, wv = t >> 6;
  int fr = lane & 15, fg = lane >> 4;
  __shared__ u16 KT[64*128];
  __shared__ u16 VT[64*128];
  __shared__ float invn_s[128];
  const u16* kb = qkv + ((size_t)(b*1536 + 512  + h*64))*NS;
  const u16* vb = qkv + ((size_t)(b*1536 + 1024 + h*64))*NS;
  int d = t >> 2, q = t & 3;

  float mloc = -3.0e38f;
  #pragma unroll
  for (int nt = 0; nt < 4; ++nt)
    #pragma unroll
    for (int s = 0; s < 4; ++s){
      u16x8 kk = *(const u16x8*)&kb[(size_t)d*NS + chunk*512 + nt*128 + q*32 + s*8];
      #pragma unroll
      for (int j = 0; j < 8; ++j) mloc = fmaxf(mloc, bf2f(kk[j]));
    }
  mloc = fmaxf(mloc, __shfl_xor(mloc, 1, 64));
  mloc = fmaxf(mloc, __shfl_xor(mloc, 2, 64));
  float sloc = 0.f;

  f32x4 acc[4][4];
  #pragma unroll
  for (int i=0;i<4;++i)
    #pragma unroll
    for (int j=0;j<4;++j) acc[i][j] = (f32x4){0.f,0.f,0.f,0.f};

  for (int nt = 0; nt < 4; ++nt){
    int n0 = chunk*512 + nt*128;
    if (nt) __syncthreads();
    u16x8 kreg[4];
    #pragma unroll
    for (int s = 0; s < 4; ++s){
      int c0 = q*32 + s*8;
      u16x8 vv = *(const u16x8*)&vb[(size_t)d*NS + n0 + c0];
      *(u16x8*)&VT[d*128 + (c0 ^ ((d&7)<<3))] = vv;
      kreg[s] = *(const u16x8*)&kb[(size_t)d*NS + n0 + c0];
    }
    __syncthreads();
    if (t < 128){
      float ss = 0.f;
      #pragma unroll
      for (int e = 0; e < 64; ++e){
        float xv = bf2f(VT[e*128 + (t ^ ((e&7)<<3))]);
        ss += xv*xv;
      }
      invn_s[t] = rsqrtf(ss);
    }
    __syncthreads();
    #pragma unroll
    for (int s = 0; s < 4; ++s){
      int c0 = q*32 + s*8;
      u16x8 kk = kreg[s];
      u16x8 ek;
      #pragma unroll
      for (int j = 0; j < 8; ++j){
        float e = __expf(bf2f(kk[j]) - mloc);
        sloc += e;
        ek[j] = f2bf(e * invn_s[c0 + j]);
      }
      *(u16x8*)&KT[d*128 + (c0 ^ ((d&7)<<3))] = ek;
    }
    __syncthreads();
    int kc = wv*32 + fg*8;
    s16x8 af[4], bfr[4];
    #pragma unroll
    for (int i=0;i<4;++i){
      int ra = i*16 + fr;
      af[i]  = *(const s16x8*)&KT[ra*128 + (kc ^ ((ra&7)<<3))];
      bfr[i] = *(const s16x8*)&VT[ra*128 + (kc ^ ((ra&7)<<3))];
    }
    #pragma unroll
    for (int i=0;i<4;++i)
      #pragma unroll
      for (int j=0;j<4;++j)
        acc[i][j] = __builtin_amdgcn_mfma_f32_16x16x32_bf16(af[i], bfr[j], acc[i][j], 0,0,0);
  }

  sloc += __shfl_xor(sloc, 1, 64);
  sloc += __shfl_xor(sloc, 2, 64);
  if (q == 0){
    size_t mb = ((size_t)bh*8 + chunk)*128;
    mS[mb + d]      = mloc;
    mS[mb + 64 + d] = sloc;
  }

  float* buf0 = (float*)KT;
  float* buf1 = (float*)VT;
  auto dump = [&](float* bf){
    #pragma unroll
    for (int i=0;i<4;++i)
      #pragma unroll
      for (int j=0;j<4;++j)
        #pragma unroll
        for (int r=0;r<4;++r) bf[((i*4+j)*4+r)*64 + lane] = acc[i][j][r];
  };
  auto addin = [&](float* bf){
    #pragma unroll
    for (int i=0;i<4;++i)
      #pragma unroll
      for (int j=0;j<4;++j)
        #pragma unroll
        for (int r=0;r<4;++r) acc[i][j][r] += bf[((i*4+j)*4+r)*64 + lane];
  };
  __syncthreads();
  if (wv==1) dump(buf0);
  if (wv==3) dump(buf1);
  __syncthreads();
  if (wv==0) addin(buf0);
  if (wv==2) addin(buf1);
  __syncthreads();
  if (wv==2) dump(buf0);
  __syncthreads();
  if (wv==0){
    addin(buf0);
    float* pp = part + ((size_t)bh*8 + chunk)*4096;
    #pragma unroll
    for (int i=0;i<4;++i)
      #pragma unroll
      for (int j=0;j<4;++j)
        #pragma unroll
        for (int r=0;r<4;++r)
          pp[(i*16+fg*4+r)*64 + j*16+fr] = acc[i][j][r];
  }
}

// ---- K4b: merge 8 chunk partials with online-softmax scales -> ctx --------
__global__ void ctxred_k(const float* __restrict__ part, const float* __restrict__ mS,
                         float* __restrict__ ctx){
  int bh = blockIdx.x, t = threadIdx.x;
  __shared__ float fs[8][64];
  if (t < 64){
    int d = t;
    float mc[8];
    float mx = -3.0e38f;
    #pragma unroll
    for (int c=0;c<8;++c){ mc[c] = mS[((size_t)bh*8 + c)*128 + d]; mx = fmaxf(mx, mc[c]); }
    float es[8]; float denom = 0.f;
    #pragma unroll
    for (int c=0;c<8;++c){
      es[c] = __expf(mc[c] - mx);
      denom += es[c] * mS[((size_t)bh*8 + c)*128 + 64 + d];
    }
    float inv = 1.0f / (denom * 4096.0f);
    #pragma unroll
    for (int c=0;c<8;++c) fs[c][d] = es[c] * inv;
  }
  __syncthreads();
  #pragma unroll
  for (int i=0;i<16;++i){
    int idx = t + i*256;
    int d = idx >> 6;
    float s = 0.f;
    #pragma unroll
    for (int ch=0; ch<8; ++ch) s += fs[ch][d] * part[((size_t)bh*8 + ch)*4096 + idx];
    ctx[(size_t)bh*4096 + idx] = s;
  }
}

// ------- K5: out = softmax_feat(q)*scale @ ctx  via MFMA, GELU, gT[b][n][c] -
__global__ __launch_bounds__(256) void attnout_k(const u16* __restrict__ qkv,
                                                 const float* __restrict__ ctx,
                                                 u16* __restrict__ gT){
  int bh = blockIdx.y;
  int b = bh >> 3, h = bh & 7;
  int n0 = blockIdx.x * 256;
  int t = threadIdx.x;
  int lane = t & 63, wv = t >> 6;
  int fr = lane & 15, fg = lane >> 4;
  __shared__ u16 P[256][72];
  __shared__ u16 cT[64][72];

  const float* cs = ctx + (size_t)bh*4096;
  #pragma unroll
  for (int i=0;i<16;++i){
    int idx = i*256 + t;
    int d = idx >> 6, e = idx & 63;
    cT[e][d] = f2bf(cs[idx]);
  }

  const u16* qb = qkv + ((size_t)(b*1536 + h*64))*NS + n0 + t;
  float p[64];
  #pragma unroll
  for (int d=0; d<64; ++d) p[d] = bf2f(qb[(size_t)d*NS]);
  float m = p[0];
  #pragma unroll
  for (int d=1; d<64; ++d) m = fmaxf(m, p[d]);
  float s = 0.f;
  #pragma unroll
  for (int d=0; d<64; ++d){ p[d] = __expf(p[d]-m); s += p[d]; }
  float inv = 0.125f / s;
  #pragma unroll
  for (int d0=0; d0<8; ++d0){
    u16x8 pk;
    #pragma unroll
    for (int j=0;j<8;++j) pk[j] = f2bf(p[d0*8+j] * inv);
    *(u16x8*)&P[t][d0*8] = pk;
  }
  __syncthreads();

  f32x4 acc[4][4];
  #pragma unroll
  for (int i=0;i<4;++i)
    #pragma unroll
    for (int j=0;j<4;++j) acc[i][j] = (f32x4){0.f,0.f,0.f,0.f};
  #pragma unroll
  for (int k=0; k<2; ++k){
    s16x8 af[4], bfr[4];
    #pragma unroll
    for (int i=0;i<4;++i){
      af[i]  = *(const s16x8*)&P[wv*64 + i*16 + fr][k*32 + fg*8];
      bfr[i] = *(const s16x8*)&cT[i*16 + fr][k*32 + fg*8];
    }
    #pragma unroll
    for (int i=0;i<4;++i)
      #pragma unroll
      for (int j=0;j<4;++j)
        acc[i][j] = __builtin_amdgcn_mfma_f32_16x16x32_bf16(af[i], bfr[j], acc[i][j], 0,0,0);
  }

  #pragma unroll
  for (int i=0;i<4;++i)
    #pragma unroll
    for (int j=0;j<4;++j)
      #pragma unroll
      for (int r=0;r<4;++r)
        P[wv*64 + i*16 + fg*4 + r][j*16 + fr] = f2bf(gelu_f(acc[i][j][r]));

  int sub = lane >> 4, e4 = (lane & 15) * 4;
  #pragma unroll
  for (int it=0; it<16; ++it){
    int row = wv*64 + it*4 + sub;
    *(u16x4*)&gT[((size_t)b*NS + n0 + row)*CD + h*64 + e4] = *(u16x4*)&P[row][e4];
  }
}

extern "C" void kernel_launch(void* const* d_in, const int* in_sizes, int n_in,
                              void* d_out, int out_size, void* d_ws, size_t ws_size,
                              hipStream_t stream) {
  const float* fmap = (const float*)d_in[0];
  const float* g1   = (const float*)d_in[1];
  const float* wqkv = (const float*)d_in[2];
  const float* wout = (const float*)d_in[3];
  const float* g2   = (const float*)d_in[4];
  float* out = (float*)d_out;

  char* ws = (char*)d_ws;
  size_t off = 0;
  auto alloc = [&](size_t bytes) -> void* {
    void* p = ws + off;
    off += (bytes + 255) & ~(size_t)255;
    return p;
  };
  u16*   qkv  = (u16*)alloc((size_t)16*1536*4096*2);
  u16*   xlnT = (u16*)alloc((size_t)16*4096*512*2);    // reused as gT
  u16*   gT   = xlnT;
  float* part = (float*)alloc((size_t)128*8*4096*4);
  float* mS   = (float*)alloc((size_t)128*8*128*4);
  float* ctx  = (float*)alloc((size_t)128*4096*4);
  u16*   w1b  = (u16*)alloc((size_t)1536*512*2);
  u16*   w2b  = (u16*)alloc((size_t)512*512*2);
  if (off > ws_size) return;

  prep_w_k<<<4096, 256, 0, stream>>>(wqkv, g1, wout, w1b, w2b);
  ln1t_k<<<dim3(128,16), 512, 0, stream>>>(fmap, xlnT);
  gemm1_k<<<3072, 512, 0, stream>>>(w1b, xlnT, qkv);
  ctxpart_k<<<dim3(8,128), 256, 0, stream>>>(qkv, part, mS);
  ctxred_k<<<128, 256, 0, stream>>>(part, mS, ctx);
  attnout_k<<<dim3(16,128), 256, 0, stream>>>(qkv, ctx, gT);
  gemm2ln_k<<<dim3(32,16), 512, 0, stream>>>(w2b, gT, g2, out);
}

// Round 11
// 324.788 us; speedup vs baseline: 1.0916x; 1.0484x over previous
//
#include <hip/hip_runtime.h>

typedef unsigned short u16;
typedef __attribute__((ext_vector_type(2))) float f32x2;
typedef __attribute__((ext_vector_type(4))) float f32x4;
typedef __attribute__((ext_vector_type(8))) short s16x8;
typedef __attribute__((ext_vector_type(8))) u16 u16x8;
typedef __attribute__((ext_vector_type(4))) u16 u16x4;

#define NB 16
#define CD 512
#define NS 4096
#define NHD 8

#define SBAR  __builtin_amdgcn_s_barrier()
#define SCHED __builtin_amdgcn_sched_barrier(0)
#define LGKM0 asm volatile("s_waitcnt lgkmcnt(0)" ::: "memory")
#define PRIO1 __builtin_amdgcn_s_setprio(1)
#define PRIO0 __builtin_amdgcn_s_setprio(0)

__device__ __forceinline__ float bf2f(u16 u){
  union { unsigned int i; float f; } z; z.i = ((unsigned int)u) << 16; return z.f;
}
__device__ __forceinline__ u16 f2bf(float f){
  union { float f; unsigned int i; } z; z.f = f;
  unsigned int i = z.i;
  return (u16)((i + 0x7fffu + ((i >> 16) & 1u)) >> 16);
}
__device__ __forceinline__ float gelu_f(float x){
  return 0.5f * x * (1.0f + erff(x * 0.70710678118654752440f));
}
__device__ __forceinline__ void gl_lds16(const u16* g, u16* l){
  __builtin_amdgcn_global_load_lds((const __attribute__((address_space(1))) void*)(g),
                                   (__attribute__((address_space(3))) void*)(l), 16, 0, 0);
}

// ---------------- K0: weights -> bf16 (g1 folded into w_qkv) ----------------
__global__ void prep_w_k(const float* __restrict__ wqkv, const float* __restrict__ g1,
                         const float* __restrict__ wout, u16* __restrict__ w1b,
                         u16* __restrict__ w2b){
  int i = blockIdx.x * 256 + threadIdx.x;
  if (i < 1536*512) {
    w1b[i] = f2bf(wqkv[i] * g1[i & 511]);
  } else {
    int j = i - 1536*512;
    w2b[j] = f2bf(wout[j]);
  }
}

// ------- K1: ChanLN over c, single global read via big-LDS staging ---------
__global__ __launch_bounds__(512) void ln1t_k(const float* __restrict__ fmap,
                                              u16* __restrict__ xlnT){
  int b = blockIdx.y, n0 = blockIdx.x * 32;
  int t = threadIdx.x;
  int lane = t & 63, wv = t >> 6;
  __shared__ float Lb[512][36];
  __shared__ u16 Tt[64][36];
  __shared__ float red1[8][8][4], red2[8][8][4];
  __shared__ float mean_s[32], rstd_s[32];

  int ng = t & 7;
  float s1[4] = {0,0,0,0}, s2[4] = {0,0,0,0};
  const float* fb = fmap + ((size_t)b*CD)*NS + n0 + ng*4;
  #pragma unroll
  for (int it = 0; it < 8; ++it){
    int q = it*512 + t;
    int c = q >> 3;
    f32x4 v = *(const f32x4*)&fb[(size_t)c*NS];
    *(f32x4*)&Lb[c][ng*4] = v;
    #pragma unroll
    for (int j = 0; j < 4; ++j){ s1[j] += v[j]; s2[j] += v[j]*v[j]; }
  }
  #pragma unroll
  for (int off = 8; off < 64; off <<= 1)
    #pragma unroll
    for (int j = 0; j < 4; ++j){
      s1[j] += __shfl_xor(s1[j], off, 64);
      s2[j] += __shfl_xor(s2[j], off, 64);
    }
  if (lane < 8){
    #pragma unroll
    for (int j = 0; j < 4; ++j){ red1[wv][lane][j] = s1[j]; red2[wv][lane][j] = s2[j]; }
  }
  __syncthreads();
  if (t < 32){
    int g = t >> 2, j = t & 3;
    float a = 0.f, bq = 0.f;
    #pragma unroll
    for (int w = 0; w < 8; ++w){ a += red1[w][g][j]; bq += red2[w][g][j]; }
    float mn = a * (1.f/512.f);
    float var = bq * (1.f/512.f) - mn*mn;
    mean_s[t] = mn; rstd_s[t] = rsqrtf(var + 1e-5f);
  }
  __syncthreads();

  for (int ct = 0; ct < 8; ++ct){
    {
      int cl = t >> 3, n4 = (t & 7) * 4;
      f32x4 v = *(const f32x4*)&Lb[ct*64 + cl][n4];
      u16x4 pk;
      #pragma unroll
      for (int j = 0; j < 4; ++j)
        pk[j] = f2bf((v[j] - mean_s[n4+j]) * rstd_s[n4+j]);
      *(u16x4*)&Tt[cl][n4] = pk;
    }
    __syncthreads();
    {
      int nr = t >> 4, c4 = t & 15;
      u16x4 w;
      #pragma unroll
      for (int j = 0; j < 4; ++j) w[j] = Tt[c4*4 + j][nr];
      *(u16x4*)&xlnT[((size_t)b*NS + n0 + nr)*CD + ct*64 + c4*4] = w;
    }
    __syncthreads();
  }
}

// ---------- K2: 256x256 GEMM, BK=64, 8-phase counted-vmcnt schedule --------
// 8 waves (2M x 4N), per-wave 128x64. LDS [2 slot][4 half][128 lines x 64]:
// half 0/1 = A quadrant mq (rows wm*128+mq*64+..), half 2/3 = B quadrant nq
// (n = wn*64+nq*32+..) -> each phase's ds_reads touch exactly ONE A-half and/
// or ONE B-half, so counted vmcnt gates are sound (never drain to 0):
// P1{rd Ah0+Bh0; stage Ah0,Bh0(t+1); mm(0,0); vmcnt(6)}
// P2{rd Bh1;     stage Bh1(t+1);     mm(0,1); vmcnt(6)}
// P3{rd Ah1;     stage Ah1(t+1);     mm(1,1)}
// P4{regs only;                      mm(1,0); vmcnt(4)}
// 0-conflict 128B-line chunk swizzle c8 = (ks*4+fg)^(li&7), source
// pre-swizzled (rule #21).
__global__ __launch_bounds__(512) void gemm1_k(const u16* __restrict__ A,
                                               const u16* __restrict__ Bm,
                                               u16* __restrict__ Cm){
  __shared__ u16 lds[2][4][8192];   // [slot][Ah0,Ah1,Bh0,Bh1][128*64]
  int bi = blockIdx.x;
  int xcd = bi & 7, r2 = bi >> 3;
  int gi = r2 / 6, yy = r2 - gi*6;
  int g  = gi*8 + xcd;
  int x  = g & 15, z = g >> 4;
  int o0 = yy*256, bn0 = x*256;
  int t = threadIdx.x;
  int lane = t & 63, wv = t >> 6;
  int wm = wv >> 2, wn = wv & 3;
  int fr = lane & 15, fg = lane >> 4;
  const u16* Ab = A + (size_t)o0*512;
  const u16* Bb = Bm + ((size_t)z*NS + bn0)*512;
  int li8 = lane >> 3, scn = lane & 7;

  f32x4 acc[8][4];
  #pragma unroll
  for (int i=0;i<8;++i)
    #pragma unroll
    for (int j=0;j<4;++j) acc[i][j] = (f32x4){0.f,0.f,0.f,0.f};
  s16x8 afr[4][2];          // current A quadrant: 4 mr x 2 ks
  s16x8 bfr[2][2][2];       // both B quadrants kept: [nq][nr][ks]

  auto stH = [&](int slot, int half, int kt){   // one half-tile: 2 gl_lds
    #pragma unroll
    for (int it=0; it<2; ++it){
      int li = it*64 + wv*8 + li8;
      int q  = scn ^ (li & 7);                  // logical k-chunk (pre-swizzled src)
      int row;
      if (half < 2) row = ((li>>6)<<7) + half*64 + (li & 63);       // A
      else          row = ((li>>5)<<6) + (half-2)*32 + (li & 31);   // B
      const u16* G = (half < 2) ? Ab : Bb;
      gl_lds16(G + (size_t)row*512 + kt + q*8, &lds[slot][half][it*4096 + wv*512]);
    }
  };
  auto ldA = [&](int slot, int mq){
    #pragma unroll
    for (int mr=0;mr<4;++mr)
      #pragma unroll
      for (int ks=0;ks<2;++ks){
        int li = wm*64 + mr*16 + fr;
        int c8 = (ks*4+fg) ^ (li & 7);
        afr[mr][ks] = *(const s16x8*)&lds[slot][mq][li*64 + c8*8];
      }
  };
  auto ldB = [&](int slot, int nq){
    #pragma unroll
    for (int nr=0;nr<2;++nr)
      #pragma unroll
      for (int ks=0;ks<2;++ks){
        int li = wn*32 + nr*16 + fr;
        int c8 = (ks*4+fg) ^ (li & 7);
        bfr[nq][nr][ks] = *(const s16x8*)&lds[slot][2+nq][li*64 + c8*8];
      }
  };
  auto mm = [&](int mq, int nq){
    #pragma unroll
    for (int mr=0;mr<4;++mr)
      #pragma unroll
      for (int nr=0;nr<2;++nr)
        #pragma unroll
        for (int ks=0;ks<2;++ks)
          acc[mq*4+mr][nq*2+nr] = __builtin_amdgcn_mfma_f32_16x16x32_bf16(
              afr[mr][ks], bfr[nq][nr][ks], acc[mq*4+mr][nq*2+nr], 0,0,0);
  };

  // prologue: tile 0, all 4 halves
  stH(0,0,0); stH(0,2,0); stH(0,3,0); stH(0,1,0);
  asm volatile("s_waitcnt vmcnt(0)" ::: "memory");
  SBAR; SCHED;

  #pragma unroll
  for (int kt=0; kt<8; ++kt){
    int slot = kt & 1, ns = slot ^ 1, kn = (kt+1)*64;
    bool F = kt < 7;
    // P1: quad (m0,n0)
    ldA(slot,0); ldB(slot,0);
    if (F){ stH(ns,0,kn); stH(ns,2,kn); }   // Ah0,Bh0 of t+1
    SBAR; LGKM0; SCHED;
    PRIO1; mm(0,0); PRIO0;
    if (F) asm volatile("s_waitcnt vmcnt(6)" ::: "memory");
    else   asm volatile("s_waitcnt vmcnt(2)" ::: "memory");
    SBAR; SCHED;
    // P2: quad (m0,n1)
    ldB(slot,1);
    if (F) stH(ns,3,kn);                    // Bh1 of t+1
    SBAR; LGKM0; SCHED;
    PRIO1; mm(0,1); PRIO0;
    if (F) asm volatile("s_waitcnt vmcnt(6)" ::: "memory");
    else   asm volatile("s_waitcnt vmcnt(0)" ::: "memory");
    SBAR; SCHED;
    // P3: quad (m1,n1)
    ldA(slot,1);
    if (F) stH(ns,1,kn);                    // Ah1 of t+1
    SBAR; LGKM0; SCHED;
    PRIO1; mm(1,1); PRIO0;
    SBAR; SCHED;
    // P4: quad (m1,n0) from regs
    PRIO1; mm(1,0); PRIO0;
    if (F) asm volatile("s_waitcnt vmcnt(4)" ::: "memory");
    SBAR; SCHED;
  }

  size_t cb = (size_t)z * 1536 * NS;
  #pragma unroll
  for (int mq=0;mq<2;++mq)
    #pragma unroll
    for (int mr=0;mr<4;++mr)
      #pragma unroll
      for (int nq=0;nq<2;++nq)
        #pragma unroll
        for (int nr=0;nr<2;++nr){
          int row = o0 + wm*128 + mq*64 + mr*16 + fg*4;
          int col = bn0 + wn*64 + nq*32 + nr*16 + fr;
          #pragma unroll
          for (int r=0;r<4;++r)
            Cm[cb + (size_t)(row+r)*NS + col] = f2bf(acc[mq*4+mr][nq*2+nr][r]);
        }
}

// ------ K6: full-column GEMM (512x128) + fused final ChanLN -> d_out -------
__global__ __launch_bounds__(512, 2) void gemm2ln_k(const u16* __restrict__ A,
                                                    const u16* __restrict__ Bm,
                                                    const float* __restrict__ g2,
                                                    float* __restrict__ out){
  __shared__ u16 lds[3][20480];   // slot: A 256 lines (32KB), B 64 lines (8KB)
  int x = blockIdx.x, z = blockIdx.y;
  int n0 = x*128;
  int t = threadIdx.x;
  int lane = t & 63, wv = t >> 6;
  int wm = wv >> 1, wn = wv & 1;
  int fr = lane & 15, fg = lane >> 4;
  const u16* Ab = A;
  const u16* Bb = Bm + ((size_t)z*NS + n0)*512;

  int l8  = lane >> 3;
  int c8d = lane & 7;

  f32x4 acc[8][4];
  #pragma unroll
  for (int i=0;i<8;++i)
    #pragma unroll
    for (int j=0;j<4;++j) acc[i][j] = (f32x4){0.f,0.f,0.f,0.f};
  s16x8 afr[4], bfr[4];

  auto stA = [&](int slot, int kt, int bt){
    int L  = bt*64 + wv*8 + l8;
    int q  = c8d ^ (l8 & 7);
    int r  = (q >> 2)*256 + L;
    int col = kt + (q & 3)*8;
    gl_lds16(Ab + (size_t)r*512 + col, &lds[slot][(bt*64 + wv*8)*64]);
  };
  auto stB = [&](int slot, int kt){
    int L  = wv*8 + l8;
    int q  = c8d ^ (l8 & 7);
    int r  = (q >> 2)*64 + L;
    int col = kt + (q & 3)*8;
    gl_lds16(Bb + (size_t)r*512 + col, &lds[slot][16384 + (wv*8)*64]);
  };
  auto ldA = [&](int slot, int h){
    #pragma unroll
    for (int mi=0;mi<4;++mi){
      int R = wm*128 + (h*4+mi)*16 + fr;
      int L = R & 255, half = R >> 8;
      int c8 = (half*4 + fg) ^ (L & 7);
      afr[mi] = *(const s16x8*)&lds[slot][L*64 + c8*8];
    }
  };
  auto ldB = [&](int slot){
    #pragma unroll
    for (int nj=0;nj<4;++nj){
      int R = wn*64 + nj*16 + fr;
      int L = R & 63, half = R >> 6;
      int c8 = (half*4 + fg) ^ (L & 7);
      bfr[nj] = *(const s16x8*)&lds[slot][16384 + L*64 + c8*8];
    }
  };
  auto mm16 = [&](int h){
    #pragma unroll
    for (int mi=0;mi<4;++mi)
      #pragma unroll
      for (int nj=0;nj<4;++nj)
        acc[h*4+mi][nj] = __builtin_amdgcn_mfma_f32_16x16x32_bf16(
            afr[mi], bfr[nj], acc[h*4+mi][nj], 0,0,0);
  };

  #pragma unroll
  for (int p=0;p<2;++p){ stA(p,p*32,0); stA(p,p*32,1); stB(p,p*32); stA(p,p*32,2); stA(p,p*32,3); }
  asm volatile("s_waitcnt vmcnt(5)" ::: "memory");
  SBAR; SCHED;

  #pragma unroll
  for (int kt=0; kt<16; ++kt){
    int slot = kt%3;
    ldA(slot,0); ldB(slot);
    if (kt<14){
      int ns = (kt+2)%3, kn = (kt+2)*32;
      stA(ns,kn,0); stA(ns,kn,1); stB(ns,kn); stA(ns,kn,2); stA(ns,kn,3);
    }
    PRIO1; mm16(0); PRIO0;
    ldA(slot,1);
    PRIO1; mm16(1); PRIO0;
    if (kt<14)       asm volatile("s_waitcnt vmcnt(5)" ::: "memory");
    else if (kt==14) asm volatile("s_waitcnt vmcnt(0)" ::: "memory");
    SBAR; SCHED;
  }

  // ---- fused LN2: stats over all 512 rows per n-col, then write d_out ----
  __syncthreads();
  float* red1 = (float*)&lds[0][0];
  float* red2 = red1 + 512;
  float* ms   = red2 + 512;
  float* rs   = ms + 128;
  float s1[4], s2[4];
  #pragma unroll
  for (int nj=0;nj<4;++nj){
    float a = 0.f, b2 = 0.f;
    #pragma unroll
    for (int mi=0;mi<8;++mi)
      #pragma unroll
      for (int r=0;r<4;++r){ float v = acc[mi][nj][r]; a += v; b2 += v*v; }
    s1[nj] = a; s2[nj] = b2;
  }
  #pragma unroll
  for (int off=16; off<64; off<<=1)
    #pragma unroll
    for (int nj=0;nj<4;++nj){
      s1[nj] += __shfl_xor(s1[nj], off, 64);
      s2[nj] += __shfl_xor(s2[nj], off, 64);
    }
  if (fg == 0){
    #pragma unroll
    for (int nj=0;nj<4;++nj){
      int c = wn*64 + nj*16 + fr;
      red1[wm*128 + c] = s1[nj];
      red2[wm*128 + c] = s2[nj];
    }
  }
  __syncthreads();
  if (t < 128){
    float a  = red1[t] + red1[128+t] + red1[256+t] + red1[384+t];
    float b2 = red2[t] + red2[128+t] + red2[256+t] + red2[384+t];
    float mn = a * (1.f/512.f);
    float var = b2 * (1.f/512.f) - mn*mn;
    ms[t] = mn; rs[t] = rsqrtf(var + 1e-5f);
  }
  __syncthreads();
  float mc[4], rc[4];
  #pragma unroll
  for (int nj=0;nj<4;++nj){
    int c = wn*64 + nj*16 + fr;
    mc[nj] = ms[c]; rc[nj] = rs[c];
  }
  float* ob = out + (size_t)z*CD*NS + n0;
  #pragma unroll
  for (int mi=0;mi<8;++mi)
    #pragma unroll
    for (int r=0;r<4;++r){
      int row = wm*128 + mi*16 + fg*4 + r;
      float gg = g2[row];
      #pragma unroll
      for (int nj=0;nj<4;++nj)
        ob[(size_t)row*NS + wn*64 + nj*16 + fr] = (acc[mi][nj][r] - mc[nj])*rc[nj]*gg;
    }
}

// ------- K4: context partials (no-max k-softmax: |k| <= ~3, exp safe) ------
__global__ __launch_bounds__(256) void ctxpart_k(const u16* __restrict__ qkv,
                                                 float* __restrict__ part,
                                                 float* __restrict__ mS){
  int chunk = blockIdx.x, bh = blockIdx.y;
  int b = bh >> 3, h = bh & 7;
  int t = threadIdx.x;
  int lane = t & 63, wv = t >> 6;
  int fr = lane & 15, fg = lane >> 4;
  __shared__ u16 KT[64*128];
  __shared__ u16 VT[64*128];
  __shared__ float invn_s[128];
  const u16* kb = qkv + ((size_t)(b*1536 + 512  + h*64))*NS;
  const u16* vb = qkv + ((size_t)(b*1536 + 1024 + h*64))*NS;
  int d = t >> 2, q = t & 3;

  float sloc = 0.f;

  f32x4 acc[4][4];
  #pragma unroll
  for (int i=0;i<4;++i)
    #pragma unroll
    for (int j=0;j<4;++j) acc[i][j] = (f32x4){0.f,0.f,0.f,0.f};

  for (int nt = 0; nt < 4; ++nt){
    int n0 = chunk*512 + nt*128;
    if (nt) __syncthreads();
    u16x8 kreg[4];
    #pragma unroll
    for (int s = 0; s < 4; ++s){
      int c0 = q*32 + s*8;
      u16x8 vv = *(const u16x8*)&vb[(size_t)d*NS + n0 + c0];
      *(u16x8*)&VT[d*128 + (c0 ^ ((d&7)<<3))] = vv;
      kreg[s] = *(const u16x8*)&kb[(size_t)d*NS + n0 + c0];
    }
    __syncthreads();
    if (t < 128){
      float ss = 0.f;
      #pragma unroll
      for (int e = 0; e < 64; ++e){
        float xv = bf2f(VT[e*128 + (t ^ ((e&7)<<3))]);
        ss += xv*xv;
      }
      invn_s[t] = rsqrtf(ss);
    }
    __syncthreads();
    #pragma unroll
    for (int s = 0; s < 4; ++s){
      int c0 = q*32 + s*8;
      u16x8 kk = kreg[s];
      u16x8 ek;
      #pragma unroll
      for (int j = 0; j < 8; ++j){
        float e = __expf(bf2f(kk[j]));
        sloc += e;
        ek[j] = f2bf(e * invn_s[c0 + j]);
      }
      *(u16x8*)&KT[d*128 + (c0 ^ ((d&7)<<3))] = ek;
    }
    __syncthreads();
    int kc = wv*32 + fg*8;
    s16x8 af[4], bfr[4];
    #pragma unroll
    for (int i=0;i<4;++i){
      int ra = i*16 + fr;
      af[i]  = *(const s16x8*)&KT[ra*128 + (kc ^ ((ra&7)<<3))];
      bfr[i] = *(const s16x8*)&VT[ra*128 + (kc ^ ((ra&7)<<3))];
    }
    #pragma unroll
    for (int i=0;i<4;++i)
      #pragma unroll
      for (int j=0;j<4;++j)
        acc[i][j] = __builtin_amdgcn_mfma_f32_16x16x32_bf16(af[i], bfr[j], acc[i][j], 0,0,0);
  }

  sloc += __shfl_xor(sloc, 1, 64);
  sloc += __shfl_xor(sloc, 2, 64);
  if (q == 0){
    size_t mb = ((size_t)bh*8 + chunk)*128;
    mS[mb + d]      = 0.0f;
    mS[mb + 64 + d] = sloc;
  }

  float* buf0 = (float*)KT;
  float* buf1 = (float*)VT;
  auto dump = [&](float* bf){
    #pragma unroll
    for (int i=0;i<4;++i)
      #pragma unroll
      for (int j=0;j<4;++j)
        #pragma unroll
        for (int r=0;r<4;++r) bf[((i*4+j)*4+r)*64 + lane] = acc[i][j][r];
  };
  auto addin = [&](float* bf){
    #pragma unroll
    for (int i=0;i<4;++i)
      #pragma unroll
      for (int j=0;j<4;++j)
        #pragma unroll
        for (int r=0;r<4;++r) acc[i][j][r] += bf[((i*4+j)*4+r)*64 + lane];
  };
  __syncthreads();
  if (wv==1) dump(buf0);
  if (wv==3) dump(buf1);
  __syncthreads();
  if (wv==0) addin(buf0);
  if (wv==2) addin(buf1);
  __syncthreads();
  if (wv==2) dump(buf0);
  __syncthreads();
  if (wv==0){
    addin(buf0);
    float* pp = part + ((size_t)bh*8 + chunk)*4096;
    #pragma unroll
    for (int i=0;i<4;++i)
      #pragma unroll
      for (int j=0;j<4;++j)
        #pragma unroll
        for (int r=0;r<4;++r)
          pp[(i*16+fg*4+r)*64 + j*16+fr] = acc[i][j][r];
  }
}

// ---- K4b: merge 8 chunk partials with online-softmax scales -> ctx --------
__global__ void ctxred_k(const float* __restrict__ part, const float* __restrict__ mS,
                         float* __restrict__ ctx){
  int bh = blockIdx.x, t = threadIdx.x;
  __shared__ float fs[8][64];
  if (t < 64){
    int d = t;
    float mc[8];
    float mx = -3.0e38f;
    #pragma unroll
    for (int c=0;c<8;++c){ mc[c] = mS[((size_t)bh*8 + c)*128 + d]; mx = fmaxf(mx, mc[c]); }
    float es[8]; float denom = 0.f;
    #pragma unroll
    for (int c=0;c<8;++c){
      es[c] = __expf(mc[c] - mx);
      denom += es[c] * mS[((size_t)bh*8 + c)*128 + 64 + d];
    }
    float inv = 1.0f / (denom * 4096.0f);
    #pragma unroll
    for (int c=0;c<8;++c) fs[c][d] = es[c] * inv;
  }
  __syncthreads();
  #pragma unroll
  for (int i=0;i<16;++i){
    int idx = t + i*256;
    int d = idx >> 6;
    float s = 0.f;
    #pragma unroll
    for (int ch=0; ch<8; ++ch) s += fs[ch][d] * part[((size_t)bh*8 + ch)*4096 + idx];
    ctx[(size_t)bh*4096 + idx] = s;
  }
}

// ------- K5: out = softmax_feat(q)*scale @ ctx  via MFMA, GELU, gT[b][n][c] -
__global__ __launch_bounds__(256) void attnout_k(const u16* __restrict__ qkv,
                                                 const float* __restrict__ ctx,
                                                 u16* __restrict__ gT){
  int bh = blockIdx.y;
  int b = bh >> 3, h = bh & 7;
  int n0 = blockIdx.x * 256;
  int t = threadIdx.x;
  int lane = t & 63, wv = t >> 6;
  int fr = lane & 15, fg = lane >> 4;
  __shared__ u16 P[256][72];
  __shared__ u16 cT[64][72];

  const float* cs = ctx + (size_t)bh*4096;
  #pragma unroll
  for (int i=0;i<16;++i){
    int idx = i*256 + t;
    int d = idx >> 6, e = idx & 63;
    cT[e][d] = f2bf(cs[idx]);
  }

  const u16* qb = qkv + ((size_t)(b*1536 + h*64))*NS + n0 + t;
  float p[64];
  #pragma unroll
  for (int d=0; d<64; ++d) p[d] = bf2f(qb[(size_t)d*NS]);
  float m = p[0];
  #pragma unroll
  for (int d=1; d<64; ++d) m = fmaxf(m, p[d]);
  float s = 0.f;
  #pragma unroll
  for (int d=0; d<64; ++d){ p[d] = __expf(p[d]-m); s += p[d]; }
  float inv = 0.125f / s;
  #pragma unroll
  for (int d0=0; d0<8; ++d0){
    u16x8 pk;
    #pragma unroll
    for (int j=0;j<8;++j) pk[j] = f2bf(p[d0*8+j] * inv);
    *(u16x8*)&P[t][d0*8] = pk;
  }
  __syncthreads();

  f32x4 acc[4][4];
  #pragma unroll
  for (int i=0;i<4;++i)
    #pragma unroll
    for (int j=0;j<4;++j) acc[i][j] = (f32x4){0.f,0.f,0.f,0.f};
  #pragma unroll
  for (int k=0; k<2; ++k){
    s16x8 af[4], bfr[4];
    #pragma unroll
    for (int i=0;i<4;++i){
      af[i]  = *(const s16x8*)&P[wv*64 + i*16 + fr][k*32 + fg*8];
      bfr[i] = *(const s16x8*)&cT[i*16 + fr][k*32 + fg*8];
    }
    #pragma unroll
    for (int i=0;i<4;++i)
      #pragma unroll
      for (int j=0;j<4;++j)
        acc[i][j] = __builtin_amdgcn_mfma_f32_16x16x32_bf16(af[i], bfr[j], acc[i][j], 0,0,0);
  }

  #pragma unroll
  for (int i=0;i<4;++i)
    #pragma unroll
    for (int j=0;j<4;++j)
      #pragma unroll
      for (int r=0;r<4;++r)
        P[wv*64 + i*16 + fg*4 + r][j*16 + fr] = f2bf(gelu_f(acc[i][j][r]));

  int sub = lane >> 4, e4 = (lane & 15) * 4;
  #pragma unroll
  for (int it=0; it<16; ++it){
    int row = wv*64 + it*4 + sub;
    *(u16x4*)&gT[((size_t)b*NS + n0 + row)*CD + h*64 + e4] = *(u16x4*)&P[row][e4];
  }
}

extern "C" void kernel_launch(void* const* d_in, const int* in_sizes, int n_in,
                              void* d_out, int out_size, void* d_ws, size_t ws_size,
                              hipStream_t stream) {
  const float* fmap = (const float*)d_in[0];
  const float* g1   = (const float*)d_in[1];
  const float* wqkv = (const float*)d_in[2];
  const float* wout = (const float*)d_in[3];
  const float* g2   = (const float*)d_in[4];
  float* out = (float*)d_out;

  char* ws = (char*)d_ws;
  size_t off = 0;
  auto alloc = [&](size_t bytes) -> void* {
    void* p = ws + off;
    off += (bytes + 255) & ~(size_t)255;
    return p;
  };
  u16*   qkv  = (u16*)alloc((size_t)16*1536*4096*2);
  u16*   xlnT = (u16*)alloc((size_t)16*4096*512*2);    // reused as gT
  u16*   gT   = xlnT;
  float* part = (float*)alloc((size_t)128*8*4096*4);
  float* mS   = (float*)alloc((size_t)128*8*128*4);
  float* ctx  = (float*)alloc((size_t)128*4096*4);
  u16*   w1b  = (u16*)alloc((size_t)1536*512*2);
  u16*   w2b  = (u16*)alloc((size_t)512*512*2);
  if (off > ws_size) return;

  prep_w_k<<<4096, 256, 0, stream>>>(wqkv, g1, wout, w1b, w2b);
  ln1t_k<<<dim3(128,16), 512, 0, stream>>>(fmap, xlnT);
  gemm1_k<<<1536, 512, 0, stream>>>(w1b, xlnT, qkv);
  ctxpart_k<<<dim3(8,128), 256, 0, stream>>>(qkv, part, mS);
  ctxred_k<<<128, 256, 0, stream>>>(part, mS, ctx);
  attnout_k<<<dim3(16,128), 256, 0, stream>>>(qkv, ctx, gT);
  gemm2ln_k<<<dim3(32,16), 512, 0, stream>>>(w2b, gT, g2, out);
}

// Round 12
// 314.193 us; speedup vs baseline: 1.1284x; 1.0337x over previous
//
#include <hip/hip_runtime.h>

typedef unsigned short u16;
typedef __attribute__((ext_vector_type(2))) float f32x2;
typedef __attribute__((ext_vector_type(4))) float f32x4;
typedef __attribute__((ext_vector_type(8))) short s16x8;
typedef __attribute__((ext_vector_type(8))) u16 u16x8;
typedef __attribute__((ext_vector_type(4))) u16 u16x4;

#define NB 16
#define CD 512
#define NS 4096
#define NHD 8

#define SBAR  __builtin_amdgcn_s_barrier()
#define SCHED __builtin_amdgcn_sched_barrier(0)
#define LGKM0 asm volatile("s_waitcnt lgkmcnt(0)" ::: "memory")
#define PRIO1 __builtin_amdgcn_s_setprio(1)
#define PRIO0 __builtin_amdgcn_s_setprio(0)

__device__ __forceinline__ float bf2f(u16 u){
  union { unsigned int i; float f; } z; z.i = ((unsigned int)u) << 16; return z.f;
}
__device__ __forceinline__ u16 f2bf(float f){
  union { float f; unsigned int i; } z; z.f = f;
  unsigned int i = z.i;
  return (u16)((i + 0x7fffu + ((i >> 16) & 1u)) >> 16);
}
__device__ __forceinline__ float gelu_f(float x){
  return 0.5f * x * (1.0f + erff(x * 0.70710678118654752440f));
}
__device__ __forceinline__ void gl_lds16(const u16* g, u16* l){
  __builtin_amdgcn_global_load_lds((const __attribute__((address_space(1))) void*)(g),
                                   (__attribute__((address_space(3))) void*)(l), 16, 0, 0);
}

// ---------------- K0: weights -> bf16 (g1 folded into w_qkv) ----------------
__global__ void prep_w_k(const float* __restrict__ wqkv, const float* __restrict__ g1,
                         const float* __restrict__ wout, u16* __restrict__ w1b,
                         u16* __restrict__ w2b){
  int i = blockIdx.x * 256 + threadIdx.x;
  if (i < 1536*512) {
    w1b[i] = f2bf(wqkv[i] * g1[i & 511]);
  } else {
    int j = i - 1536*512;
    w2b[j] = f2bf(wout[j]);
  }
}

// ------- K1: ChanLN over c, single global read via big-LDS staging ---------
__global__ __launch_bounds__(512) void ln1t_k(const float* __restrict__ fmap,
                                              u16* __restrict__ xlnT){
  int b = blockIdx.y, n0 = blockIdx.x * 32;
  int t = threadIdx.x;
  int lane = t & 63, wv = t >> 6;
  __shared__ float Lb[512][36];
  __shared__ u16 Tt[64][36];
  __shared__ float red1[8][8][4], red2[8][8][4];
  __shared__ float mean_s[32], rstd_s[32];

  int ng = t & 7;
  float s1[4] = {0,0,0,0}, s2[4] = {0,0,0,0};
  const float* fb = fmap + ((size_t)b*CD)*NS + n0 + ng*4;
  #pragma unroll
  for (int it = 0; it < 8; ++it){
    int q = it*512 + t;
    int c = q >> 3;
    f32x4 v = *(const f32x4*)&fb[(size_t)c*NS];
    *(f32x4*)&Lb[c][ng*4] = v;
    #pragma unroll
    for (int j = 0; j < 4; ++j){ s1[j] += v[j]; s2[j] += v[j]*v[j]; }
  }
  #pragma unroll
  for (int off = 8; off < 64; off <<= 1)
    #pragma unroll
    for (int j = 0; j < 4; ++j){
      s1[j] += __shfl_xor(s1[j], off, 64);
      s2[j] += __shfl_xor(s2[j], off, 64);
    }
  if (lane < 8){
    #pragma unroll
    for (int j = 0; j < 4; ++j){ red1[wv][lane][j] = s1[j]; red2[wv][lane][j] = s2[j]; }
  }
  __syncthreads();
  if (t < 32){
    int g = t >> 2, j = t & 3;
    float a = 0.f, bq = 0.f;
    #pragma unroll
    for (int w = 0; w < 8; ++w){ a += red1[w][g][j]; bq += red2[w][g][j]; }
    float mn = a * (1.f/512.f);
    float var = bq * (1.f/512.f) - mn*mn;
    mean_s[t] = mn; rstd_s[t] = rsqrtf(var + 1e-5f);
  }
  __syncthreads();

  for (int ct = 0; ct < 8; ++ct){
    {
      int cl = t >> 3, n4 = (t & 7) * 4;
      f32x4 v = *(const f32x4*)&Lb[ct*64 + cl][n4];
      u16x4 pk;
      #pragma unroll
      for (int j = 0; j < 4; ++j)
        pk[j] = f2bf((v[j] - mean_s[n4+j]) * rstd_s[n4+j]);
      *(u16x4*)&Tt[cl][n4] = pk;
    }
    __syncthreads();
    {
      int nr = t >> 4, c4 = t & 15;
      u16x4 w;
      #pragma unroll
      for (int j = 0; j < 4; ++j) w[j] = Tt[c4*4 + j][nr];
      *(u16x4*)&xlnT[((size_t)b*NS + n0 + nr)*CD + ct*64 + c4*4] = w;
    }
    __syncthreads();
  }
}

// ---------- K2: 256x256 GEMM, BK=64, lean 2-phase counted-vmcnt ------------
// 8 waves (2M x 4N), per-wave 128x64. LDS [2 slot][4 half][128x64]. Phases:
// P1{rd Ah0,Bh0,Bh1 (16 ds_read); stage Ah0,Bh0,Bh1(t+1); 32 MFMA; vmcnt(6)}
// P2{rd Ah1 (8 ds_read);           stage Ah1(t+1);         32 MFMA; vmcnt(2)}
// One barrier per phase; NO lgkm walls (compiler interleaves ds_read w/ MFMA
// via fine-grained lgkmcnt; no cross-wave dep before MFMA). Gates verified:
// steady-state outstanding=8 at each gate; oldest drained = exactly the
// halves the next phase reads; never drains to 0 mid-loop.
__global__ __launch_bounds__(512) void gemm1_k(const u16* __restrict__ A,
                                               const u16* __restrict__ Bm,
                                               u16* __restrict__ Cm){
  __shared__ u16 lds[2][4][8192];   // [slot][Ah0,Ah1,Bh0,Bh1][128*64]
  int bi = blockIdx.x;
  int xcd = bi & 7, r2 = bi >> 3;
  int gi = r2 / 6, yy = r2 - gi*6;
  int g  = gi*8 + xcd;
  int x  = g & 15, z = g >> 4;
  int o0 = yy*256, bn0 = x*256;
  int t = threadIdx.x;
  int lane = t & 63, wv = t >> 6;
  int wm = wv >> 2, wn = wv & 3;
  int fr = lane & 15, fg = lane >> 4;
  const u16* Ab = A + (size_t)o0*512;
  const u16* Bb = Bm + ((size_t)z*NS + bn0)*512;
  int li8 = lane >> 3, scn = lane & 7;

  f32x4 acc[8][4];
  #pragma unroll
  for (int i=0;i<8;++i)
    #pragma unroll
    for (int j=0;j<4;++j) acc[i][j] = (f32x4){0.f,0.f,0.f,0.f};
  s16x8 afr[4][2];          // current A quadrant: 4 mr x 2 ks
  s16x8 bfr[2][2][2];       // both B quadrants kept: [nq][nr][ks]

  auto stH = [&](int slot, int half, int kt){   // one half-tile: 2 gl_lds
    #pragma unroll
    for (int it=0; it<2; ++it){
      int li = it*64 + wv*8 + li8;
      int q  = scn ^ (li & 7);                  // logical k-chunk (pre-swizzled src)
      int row;
      if (half < 2) row = ((li>>6)<<7) + half*64 + (li & 63);       // A
      else          row = ((li>>5)<<6) + (half-2)*32 + (li & 31);   // B
      const u16* G = (half < 2) ? Ab : Bb;
      gl_lds16(G + (size_t)row*512 + kt + q*8, &lds[slot][half][it*4096 + wv*512]);
    }
  };
  auto ldA = [&](int slot, int mq){
    #pragma unroll
    for (int mr=0;mr<4;++mr)
      #pragma unroll
      for (int ks=0;ks<2;++ks){
        int li = wm*64 + mr*16 + fr;
        int c8 = (ks*4+fg) ^ (li & 7);
        afr[mr][ks] = *(const s16x8*)&lds[slot][mq][li*64 + c8*8];
      }
  };
  auto ldB = [&](int slot, int nq){
    #pragma unroll
    for (int nr=0;nr<2;++nr)
      #pragma unroll
      for (int ks=0;ks<2;++ks){
        int li = wn*32 + nr*16 + fr;
        int c8 = (ks*4+fg) ^ (li & 7);
        bfr[nq][nr][ks] = *(const s16x8*)&lds[slot][2+nq][li*64 + c8*8];
      }
  };
  auto mm = [&](int mq, int nq){
    #pragma unroll
    for (int mr=0;mr<4;++mr)
      #pragma unroll
      for (int nr=0;nr<2;++nr)
        #pragma unroll
        for (int ks=0;ks<2;++ks)
          acc[mq*4+mr][nq*2+nr] = __builtin_amdgcn_mfma_f32_16x16x32_bf16(
              afr[mr][ks], bfr[nq][nr][ks], acc[mq*4+mr][nq*2+nr], 0,0,0);
  };

  // prologue: tile 0, halves in consumption order Ah0,Bh0,Bh1,Ah1
  stH(0,0,0); stH(0,2,0); stH(0,3,0); stH(0,1,0);
  asm volatile("s_waitcnt vmcnt(2)" ::: "memory");   // first 3 halves landed
  SBAR; SCHED;

  #pragma unroll
  for (int kt=0; kt<8; ++kt){
    int slot = kt & 1, ns = slot ^ 1, kn = (kt+1)*64;
    bool F = kt < 7;
    // P1: quads (m0,n0) + (m0,n1)
    ldA(slot,0); ldB(slot,0); ldB(slot,1);
    if (F){ stH(ns,0,kn); stH(ns,2,kn); stH(ns,3,kn); }
    PRIO1; mm(0,0); mm(0,1); PRIO0;
    if (F) asm volatile("s_waitcnt vmcnt(6)" ::: "memory");   // prev P2's Ah1 done
    else   asm volatile("s_waitcnt vmcnt(0)" ::: "memory");
    SBAR; SCHED;
    // P2: quads (m1,n1) + (m1,n0)
    ldA(slot,1);
    if (F) stH(ns,1,kn);
    PRIO1; mm(1,1); mm(1,0); PRIO0;
    if (F) asm volatile("s_waitcnt vmcnt(2)" ::: "memory");   // P1's 3 halves done
    SBAR; SCHED;
  }

  size_t cb = (size_t)z * 1536 * NS;
  #pragma unroll
  for (int mq=0;mq<2;++mq)
    #pragma unroll
    for (int mr=0;mr<4;++mr)
      #pragma unroll
      for (int nq=0;nq<2;++nq)
        #pragma unroll
        for (int nr=0;nr<2;++nr){
          int row = o0 + wm*128 + mq*64 + mr*16 + fg*4;
          int col = bn0 + wn*64 + nq*32 + nr*16 + fr;
          #pragma unroll
          for (int r=0;r<4;++r)
            Cm[cb + (size_t)(row+r)*NS + col] = f2bf(acc[mq*4+mr][nq*2+nr][r]);
        }
}

// ------ K6: full-column GEMM (512x128) + fused final ChanLN -> d_out -------
__global__ __launch_bounds__(512, 2) void gemm2ln_k(const u16* __restrict__ A,
                                                    const u16* __restrict__ Bm,
                                                    const float* __restrict__ g2,
                                                    float* __restrict__ out){
  __shared__ u16 lds[3][20480];   // slot: A 256 lines (32KB), B 64 lines (8KB)
  int x = blockIdx.x, z = blockIdx.y;
  int n0 = x*128;
  int t = threadIdx.x;
  int lane = t & 63, wv = t >> 6;
  int wm = wv >> 1, wn = wv & 1;
  int fr = lane & 15, fg = lane >> 4;
  const u16* Ab = A;
  const u16* Bb = Bm + ((size_t)z*NS + n0)*512;

  int l8  = lane >> 3;
  int c8d = lane & 7;

  f32x4 acc[8][4];
  #pragma unroll
  for (int i=0;i<8;++i)
    #pragma unroll
    for (int j=0;j<4;++j) acc[i][j] = (f32x4){0.f,0.f,0.f,0.f};
  s16x8 afr[4], bfr[4];

  auto stA = [&](int slot, int kt, int bt){
    int L  = bt*64 + wv*8 + l8;
    int q  = c8d ^ (l8 & 7);
    int r  = (q >> 2)*256 + L;
    int col = kt + (q & 3)*8;
    gl_lds16(Ab + (size_t)r*512 + col, &lds[slot][(bt*64 + wv*8)*64]);
  };
  auto stB = [&](int slot, int kt){
    int L  = wv*8 + l8;
    int q  = c8d ^ (l8 & 7);
    int r  = (q >> 2)*64 + L;
    int col = kt + (q & 3)*8;
    gl_lds16(Bb + (size_t)r*512 + col, &lds[slot][16384 + (wv*8)*64]);
  };
  auto ldA = [&](int slot, int h){
    #pragma unroll
    for (int mi=0;mi<4;++mi){
      int R = wm*128 + (h*4+mi)*16 + fr;
      int L = R & 255, half = R >> 8;
      int c8 = (half*4 + fg) ^ (L & 7);
      afr[mi] = *(const s16x8*)&lds[slot][L*64 + c8*8];
    }
  };
  auto ldB = [&](int slot){
    #pragma unroll
    for (int nj=0;nj<4;++nj){
      int R = wn*64 + nj*16 + fr;
      int L = R & 63, half = R >> 6;
      int c8 = (half*4 + fg) ^ (L & 7);
      bfr[nj] = *(const s16x8*)&lds[slot][16384 + L*64 + c8*8];
    }
  };
  auto mm16 = [&](int h){
    #pragma unroll
    for (int mi=0;mi<4;++mi)
      #pragma unroll
      for (int nj=0;nj<4;++nj)
        acc[h*4+mi][nj] = __builtin_amdgcn_mfma_f32_16x16x32_bf16(
            afr[mi], bfr[nj], acc[h*4+mi][nj], 0,0,0);
  };

  #pragma unroll
  for (int p=0;p<2;++p){ stA(p,p*32,0); stA(p,p*32,1); stB(p,p*32); stA(p,p*32,2); stA(p,p*32,3); }
  asm volatile("s_waitcnt vmcnt(5)" ::: "memory");
  SBAR; SCHED;

  #pragma unroll
  for (int kt=0; kt<16; ++kt){
    int slot = kt%3;
    ldA(slot,0); ldB(slot);
    if (kt<14){
      int ns = (kt+2)%3, kn = (kt+2)*32;
      stA(ns,kn,0); stA(ns,kn,1); stB(ns,kn); stA(ns,kn,2); stA(ns,kn,3);
    }
    PRIO1; mm16(0); PRIO0;
    ldA(slot,1);
    PRIO1; mm16(1); PRIO0;
    if (kt<14)       asm volatile("s_waitcnt vmcnt(5)" ::: "memory");
    else if (kt==14) asm volatile("s_waitcnt vmcnt(0)" ::: "memory");
    SBAR; SCHED;
  }

  // ---- fused LN2: stats over all 512 rows per n-col, then write d_out ----
  __syncthreads();
  float* red1 = (float*)&lds[0][0];
  float* red2 = red1 + 512;
  float* ms   = red2 + 512;
  float* rs   = ms + 128;
  float s1[4], s2[4];
  #pragma unroll
  for (int nj=0;nj<4;++nj){
    float a = 0.f, b2 = 0.f;
    #pragma unroll
    for (int mi=0;mi<8;++mi)
      #pragma unroll
      for (int r=0;r<4;++r){ float v = acc[mi][nj][r]; a += v; b2 += v*v; }
    s1[nj] = a; s2[nj] = b2;
  }
  #pragma unroll
  for (int off=16; off<64; off<<=1)
    #pragma unroll
    for (int nj=0;nj<4;++nj){
      s1[nj] += __shfl_xor(s1[nj], off, 64);
      s2[nj] += __shfl_xor(s2[nj], off, 64);
    }
  if (fg == 0){
    #pragma unroll
    for (int nj=0;nj<4;++nj){
      int c = wn*64 + nj*16 + fr;
      red1[wm*128 + c] = s1[nj];
      red2[wm*128 + c] = s2[nj];
    }
  }
  __syncthreads();
  if (t < 128){
    float a  = red1[t] + red1[128+t] + red1[256+t] + red1[384+t];
    float b2 = red2[t] + red2[128+t] + red2[256+t] + red2[384+t];
    float mn = a * (1.f/512.f);
    float var = b2 * (1.f/512.f) - mn*mn;
    ms[t] = mn; rs[t] = rsqrtf(var + 1e-5f);
  }
  __syncthreads();
  float mc[4], rc[4];
  #pragma unroll
  for (int nj=0;nj<4;++nj){
    int c = wn*64 + nj*16 + fr;
    mc[nj] = ms[c]; rc[nj] = rs[c];
  }
  float* ob = out + (size_t)z*CD*NS + n0;
  #pragma unroll
  for (int mi=0;mi<8;++mi)
    #pragma unroll
    for (int r=0;r<4;++r){
      int row = wm*128 + mi*16 + fg*4 + r;
      float gg = g2[row];
      #pragma unroll
      for (int nj=0;nj<4;++nj)
        ob[(size_t)row*NS + wn*64 + nj*16 + fr] = (acc[mi][nj][r] - mc[nj])*rc[nj]*gg;
    }
}

// ------- K4: context partials (no-max k-softmax: |k| <= ~3, exp safe) ------
__global__ __launch_bounds__(256) void ctxpart_k(const u16* __restrict__ qkv,
                                                 float* __restrict__ part,
                                                 float* __restrict__ mS){
  int chunk = blockIdx.x, bh = blockIdx.y;
  int b = bh >> 3, h = bh & 7;
  int t = threadIdx.x;
  int lane = t & 63, wv = t >> 6;
  int fr = lane & 15, fg = lane >> 4;
  __shared__ u16 KT[64*128];
  __shared__ u16 VT[64*128];
  __shared__ float invn_s[128];
  const u16* kb = qkv + ((size_t)(b*1536 + 512  + h*64))*NS;
  const u16* vb = qkv + ((size_t)(b*1536 + 1024 + h*64))*NS;
  int d = t >> 2, q = t & 3;

  float sloc = 0.f;

  f32x4 acc[4][4];
  #pragma unroll
  for (int i=0;i<4;++i)
    #pragma unroll
    for (int j=0;j<4;++j) acc[i][j] = (f32x4){0.f,0.f,0.f,0.f};

  for (int nt = 0; nt < 4; ++nt){
    int n0 = chunk*512 + nt*128;
    if (nt) __syncthreads();
    u16x8 kreg[4];
    #pragma unroll
    for (int s = 0; s < 4; ++s){
      int c0 = q*32 + s*8;
      u16x8 vv = *(const u16x8*)&vb[(size_t)d*NS + n0 + c0];
      *(u16x8*)&VT[d*128 + (c0 ^ ((d&7)<<3))] = vv;
      kreg[s] = *(const u16x8*)&kb[(size_t)d*NS + n0 + c0];
    }
    __syncthreads();
    {
      // all 256 threads: col = t>>1, e-half = t&1 (32 rows each), shfl merge
      int col = t >> 1, half = t & 1;
      float ss = 0.f;
      #pragma unroll
      for (int e2 = 0; e2 < 32; ++e2){
        int e = half*32 + e2;
        float xv = bf2f(VT[e*128 + (col ^ ((e&7)<<3))]);
        ss += xv*xv;
      }
      ss += __shfl_xor(ss, 1, 64);
      if (half == 0) invn_s[col] = rsqrtf(ss);
    }
    __syncthreads();
    #pragma unroll
    for (int s = 0; s < 4; ++s){
      int c0 = q*32 + s*8;
      u16x8 kk = kreg[s];
      u16x8 ek;
      #pragma unroll
      for (int j = 0; j < 8; ++j){
        float e = __expf(bf2f(kk[j]));
        sloc += e;
        ek[j] = f2bf(e * invn_s[c0 + j]);
      }
      *(u16x8*)&KT[d*128 + (c0 ^ ((d&7)<<3))] = ek;
    }
    __syncthreads();
    int kc = wv*32 + fg*8;
    s16x8 af[4], bfr[4];
    #pragma unroll
    for (int i=0;i<4;++i){
      int ra = i*16 + fr;
      af[i]  = *(const s16x8*)&KT[ra*128 + (kc ^ ((ra&7)<<3))];
      bfr[i] = *(const s16x8*)&VT[ra*128 + (kc ^ ((ra&7)<<3))];
    }
    #pragma unroll
    for (int i=0;i<4;++i)
      #pragma unroll
      for (int j=0;j<4;++j)
        acc[i][j] = __builtin_amdgcn_mfma_f32_16x16x32_bf16(af[i], bfr[j], acc[i][j], 0,0,0);
  }

  sloc += __shfl_xor(sloc, 1, 64);
  sloc += __shfl_xor(sloc, 2, 64);
  if (q == 0){
    size_t mb = ((size_t)bh*8 + chunk)*128;
    mS[mb + d]      = 0.0f;
    mS[mb + 64 + d] = sloc;
  }

  float* buf0 = (float*)KT;
  float* buf1 = (float*)VT;
  auto dump = [&](float* bf){
    #pragma unroll
    for (int i=0;i<4;++i)
      #pragma unroll
      for (int j=0;j<4;++j)
        #pragma unroll
        for (int r=0;r<4;++r) bf[((i*4+j)*4+r)*64 + lane] = acc[i][j][r];
  };
  auto addin = [&](float* bf){
    #pragma unroll
    for (int i=0;i<4;++i)
      #pragma unroll
      for (int j=0;j<4;++j)
        #pragma unroll
        for (int r=0;r<4;++r) acc[i][j][r] += bf[((i*4+j)*4+r)*64 + lane];
  };
  __syncthreads();
  if (wv==1) dump(buf0);
  if (wv==3) dump(buf1);
  __syncthreads();
  if (wv==0) addin(buf0);
  if (wv==2) addin(buf1);
  __syncthreads();
  if (wv==2) dump(buf0);
  __syncthreads();
  if (wv==0){
    addin(buf0);
    float* pp = part + ((size_t)bh*8 + chunk)*4096;
    #pragma unroll
    for (int i=0;i<4;++i)
      #pragma unroll
      for (int j=0;j<4;++j)
        #pragma unroll
        for (int r=0;r<4;++r)
          pp[(i*16+fg*4+r)*64 + j*16+fr] = acc[i][j][r];
  }
}

// ---- K4b: merge 8 chunk partials with online-softmax scales -> ctx --------
__global__ void ctxred_k(const float* __restrict__ part, const float* __restrict__ mS,
                         float* __restrict__ ctx){
  int bh = blockIdx.x, t = threadIdx.x;
  __shared__ float fs[8][64];
  if (t < 64){
    int d = t;
    float mc[8];
    float mx = -3.0e38f;
    #pragma unroll
    for (int c=0;c<8;++c){ mc[c] = mS[((size_t)bh*8 + c)*128 + d]; mx = fmaxf(mx, mc[c]); }
    float es[8]; float denom = 0.f;
    #pragma unroll
    for (int c=0;c<8;++c){
      es[c] = __expf(mc[c] - mx);
      denom += es[c] * mS[((size_t)bh*8 + c)*128 + 64 + d];
    }
    float inv = 1.0f / (denom * 4096.0f);
    #pragma unroll
    for (int c=0;c<8;++c) fs[c][d] = es[c] * inv;
  }
  __syncthreads();
  #pragma unroll
  for (int i=0;i<16;++i){
    int idx = t + i*256;
    int d = idx >> 6;
    float s = 0.f;
    #pragma unroll
    for (int ch=0; ch<8; ++ch) s += fs[ch][d] * part[((size_t)bh*8 + ch)*4096 + idx];
    ctx[(size_t)bh*4096 + idx] = s;
  }
}

// ------- K5: out = softmax_feat(q)*scale @ ctx  via MFMA, GELU, gT[b][n][c] -
__global__ __launch_bounds__(256) void attnout_k(const u16* __restrict__ qkv,
                                                 const float* __restrict__ ctx,
                                                 u16* __restrict__ gT){
  int bh = blockIdx.y;
  int b = bh >> 3, h = bh & 7;
  int n0 = blockIdx.x * 256;
  int t = threadIdx.x;
  int lane = t & 63, wv = t >> 6;
  int fr = lane & 15, fg = lane >> 4;
  __shared__ u16 P[256][72];
  __shared__ u16 cT[64][72];

  const float* cs = ctx + (size_t)bh*4096;
  #pragma unroll
  for (int i=0;i<16;++i){
    int idx = i*256 + t;
    int d = idx >> 6, e = idx & 63;
    cT[e][d] = f2bf(cs[idx]);
  }

  const u16* qb = qkv + ((size_t)(b*1536 + h*64))*NS + n0 + t;
  float p[64];
  #pragma unroll
  for (int d=0; d<64; ++d) p[d] = bf2f(qb[(size_t)d*NS]);
  float m = p[0];
  #pragma unroll
  for (int d=1; d<64; ++d) m = fmaxf(m, p[d]);
  float s = 0.f;
  #pragma unroll
  for (int d=0; d<64; ++d){ p[d] = __expf(p[d]-m); s += p[d]; }
  float inv = 0.125f / s;
  #pragma unroll
  for (int d0=0; d0<8; ++d0){
    u16x8 pk;
    #pragma unroll
    for (int j=0;j<8;++j) pk[j] = f2bf(p[d0*8+j] * inv);
    *(u16x8*)&P[t][d0*8] = pk;
  }
  __syncthreads();

  f32x4 acc[4][4];
  #pragma unroll
  for (int i=0;i<4;++i)
    #pragma unroll
    for (int j=0;j<4;++j) acc[i][j] = (f32x4){0.f,0.f,0.f,0.f};
  #pragma unroll
  for (int k=0; k<2; ++k){
    s16x8 af[4], bfr[4];
    #pragma unroll
    for (int i=0;i<4;++i){
      af[i]  = *(const s16x8*)&P[wv*64 + i*16 + fr][k*32 + fg*8];
      bfr[i] = *(const s16x8*)&cT[i*16 + fr][k*32 + fg*8];
    }
    #pragma unroll
    for (int i=0;i<4;++i)
      #pragma unroll
      for (int j=0;j<4;++j)
        acc[i][j] = __builtin_amdgcn_mfma_f32_16x16x32_bf16(af[i], bfr[j], acc[i][j], 0,0,0);
  }

  #pragma unroll
  for (int i=0;i<4;++i)
    #pragma unroll
    for (int j=0;j<4;++j)
      #pragma unroll
      for (int r=0;r<4;++r)
        P[wv*64 + i*16 + fg*4 + r][j*16 + fr] = f2bf(gelu_f(acc[i][j][r]));

  int sub = lane >> 4, e4 = (lane & 15) * 4;
  #pragma unroll
  for (int it=0; it<16; ++it){
    int row = wv*64 + it*4 + sub;
    *(u16x4*)&gT[((size_t)b*NS + n0 + row)*CD + h*64 + e4] = *(u16x4*)&P[row][e4];
  }
}

extern "C" void kernel_launch(void* const* d_in, const int* in_sizes, int n_in,
                              void* d_out, int out_size, void* d_ws, size_t ws_size,
                              hipStream_t stream) {
  const float* fmap = (const float*)d_in[0];
  const float* g1   = (const float*)d_in[1];
  const float* wqkv = (const float*)d_in[2];
  const float* wout = (const float*)d_in[3];
  const float* g2   = (const float*)d_in[4];
  float* out = (float*)d_out;

  char* ws = (char*)d_ws;
  size_t off = 0;
  auto alloc = [&](size_t bytes) -> void* {
    void* p = ws + off;
    off += (bytes + 255) & ~(size_t)255;
    return p;
  };
  u16*   qkv  = (u16*)alloc((size_t)16*1536*4096*2);
  u16*   xlnT = (u16*)alloc((size_t)16*4096*512*2);    // reused as gT
  u16*   gT   = xlnT;
  float* part = (float*)alloc((size_t)128*8*4096*4);
  float* mS   = (float*)alloc((size_t)128*8*128*4);
  float* ctx  = (float*)alloc((size_t)128*4096*4);
  u16*   w1b  = (u16*)alloc((size_t)1536*512*2);
  u16*   w2b  = (u16*)alloc((size_t)512*512*2);
  if (off > ws_size) return;

  prep_w_k<<<4096, 256, 0, stream>>>(wqkv, g1, wout, w1b, w2b);
  ln1t_k<<<dim3(128,16), 512, 0, stream>>>(fmap, xlnT);
  gemm1_k<<<1536, 512, 0, stream>>>(w1b, xlnT, qkv);
  ctxpart_k<<<dim3(8,128), 256, 0, stream>>>(qkv, part, mS);
  ctxred_k<<<128, 256, 0, stream>>>(part, mS, ctx);
  attnout_k<<<dim3(16,128), 256, 0, stream>>>(qkv, ctx, gT);
  gemm2ln_k<<<dim3(32,16), 512, 0, stream>>>(w2b, gT, g2, out);
}